// Round 1
// baseline (6636.903 us; speedup 1.0000x reference)
//
#include <hip/hip_runtime.h>
#include <cstdint>

// Problem constants
// B=16, C=64, Np=128, D=128, HT=4 (dh=32), HS=4, F=128, DK=64, TOPK=8

__device__ __forceinline__ unsigned short f2bf(float f) {
    unsigned int u = __float_as_uint(f);
    u += 0x7fffu + ((u >> 16) & 1u);   // round-to-nearest-even (finite values)
    return (unsigned short)(u >> 16);
}
__device__ __forceinline__ float bf2f(unsigned short u) {
    return __uint_as_float(((unsigned int)u) << 16);
}

// dot of 128-elem register array with contiguous (wave-uniform) weight row
__device__ __forceinline__ float dot128(const float* __restrict__ a, const float* __restrict__ w) {
    float s0 = 0.f, s1 = 0.f, s2 = 0.f, s3 = 0.f;
#pragma unroll
    for (int d = 0; d < 128; d += 4) {
        s0 += a[d]     * w[d];
        s1 += a[d + 1] * w[d + 1];
        s2 += a[d + 2] * w[d + 2];
        s3 += a[d + 3] * w[d + 3];
    }
    return (s0 + s1) + (s2 + s3);
}

// LayerNorm over 128 register-resident values (in-place safe)
__device__ __forceinline__ void layernorm128(const float* __restrict__ v, float* __restrict__ o,
                                             const float* __restrict__ g, const float* __restrict__ b) {
    float s0 = 0.f, s1 = 0.f, s2 = 0.f, s3 = 0.f;
#pragma unroll
    for (int d = 0; d < 128; d += 4) { s0 += v[d]; s1 += v[d+1]; s2 += v[d+2]; s3 += v[d+3]; }
    float mu = ((s0 + s1) + (s2 + s3)) * 0.0078125f;
    s0 = s1 = s2 = s3 = 0.f;
#pragma unroll
    for (int d = 0; d < 128; d += 4) {
        float a0 = v[d] - mu, a1 = v[d+1] - mu, a2 = v[d+2] - mu, a3 = v[d+3] - mu;
        s0 += a0 * a0; s1 += a1 * a1; s2 += a2 * a2; s3 += a3 * a3;
    }
    float rs = rsqrtf(((s0 + s1) + (s2 + s3)) * 0.0078125f + 1e-5f);
#pragma unroll
    for (int d = 0; d < 128; d++) o[d] = (v[d] - mu) * rs * g[d] + b[d];
}

// ---------------------------------------------------------------------------
// Kernel 0: transpose attn_out_w (128x128) and ff2_w (128x512) so the temporal
// kernel can read weight rows contiguously (wave-uniform -> s_load operands).
__global__ void transpose_w_kernel(const float* __restrict__ wout, const float* __restrict__ w2,
                                   float* __restrict__ woutT, float* __restrict__ w2T) {
    int tid = blockIdx.x * 256 + threadIdx.x;   // 0 .. 65535
    if (tid < 128 * 128) {
        int i = tid / 128, j = tid % 128;
        woutT[j * 128 + i] = wout[i * 128 + j];
    }
    // 128*512 = 65536 = grid size exactly
    {
        int i = tid / 512, j = tid % 512;
        w2T[j * 128 + i] = w2[i * 512 + j];
    }
}

// ---------------------------------------------------------------------------
// Kernel 1: fused temporal transformer block. One block per sequence n=(b,c),
// one thread per token p. x (residual) and h (LN output) live in VGPRs.
// Weight operands are wave-uniform -> scalar loads. K/V/Q per head in LDS.
__global__ __launch_bounds__(128, 1)
void temporal_kernel(const float* __restrict__ Hin,
                     const float* __restrict__ Wqkv, const float* __restrict__ bqkv,
                     const float* __restrict__ woutT, const float* __restrict__ bout,
                     const float* __restrict__ g1, const float* __restrict__ b1v,
                     const float* __restrict__ g2, const float* __restrict__ b2v,
                     const float* __restrict__ W1, const float* __restrict__ bf1,
                     const float* __restrict__ w2T, const float* __restrict__ bf2,
                     const float* __restrict__ tg, const float* __restrict__ tbv,
                     float* __restrict__ Htemp) {
    __shared__ float kh[128][36];   // pitch 36 -> 16B-aligned rows for float4
    __shared__ float vh[128][36];
    __shared__ float qh[128][36];

    const int n = blockIdx.x;
    const int p = threadIdx.x;
    const float* xrow = Hin + ((long)n * 128 + p) * 128;

    float x[128], h[128];
#pragma unroll
    for (int d = 0; d < 128; d += 4) {
        float4 t = *(const float4*)(xrow + d);
        x[d] = t.x; x[d+1] = t.y; x[d+2] = t.z; x[d+3] = t.w;
    }
    layernorm128(x, h, g1, b1v);

    for (int hh = 0; hh < 4; hh++) {
        // q/k/v rows for this token, this head (32 each)
        for (int j = 0; j < 32; j++) {
            int cq = hh * 32 + j;
            qh[p][j] = dot128(h, Wqkv + (long)cq * 128)         + bqkv[cq];
            kh[p][j] = dot128(h, Wqkv + (long)(128 + cq) * 128) + bqkv[128 + cq];
            vh[p][j] = dot128(h, Wqkv + (long)(256 + cq) * 128) + bqkv[256 + cq];
        }
        float q[32];
#pragma unroll
        for (int j = 0; j < 32; j++) q[j] = qh[p][j];
        __syncthreads();

        // online-softmax attention over all 128 keys (broadcast LDS reads)
        float m = -1e30f, l = 0.f, o[32];
#pragma unroll
        for (int j = 0; j < 32; j++) o[j] = 0.f;
        for (int t = 0; t < 128; t++) {
            float a0 = 0.f, a1 = 0.f, a2 = 0.f, a3 = 0.f;
#pragma unroll
            for (int j = 0; j < 32; j += 4) {
                float4 k4 = *(const float4*)&kh[t][j];
                a0 += q[j] * k4.x; a1 += q[j+1] * k4.y; a2 += q[j+2] * k4.z; a3 += q[j+3] * k4.w;
            }
            float s = ((a0 + a1) + (a2 + a3)) * 0.17677669529663687f;   // 1/sqrt(32)
            float nm = fmaxf(m, s);
            float corr = __expf(m - nm);
            float pv = __expf(s - nm);
            l = l * corr + pv;
#pragma unroll
            for (int j = 0; j < 32; j += 4) {
                float4 v4 = *(const float4*)&vh[t][j];
                o[j]   = o[j]   * corr + pv * v4.x;
                o[j+1] = o[j+1] * corr + pv * v4.y;
                o[j+2] = o[j+2] * corr + pv * v4.z;
                o[j+3] = o[j+3] * corr + pv * v4.w;
            }
            m = nm;
        }
        float rinv = 1.f / l;
#pragma unroll
        for (int j = 0; j < 32; j++) qh[p][j] = o[j] * rinv;   // reuse qh to hold o
        __syncthreads();   // all kh/vh reads done before next head overwrites

        // output projection for this head's 32 columns, accumulate into x
        for (int j = 0; j < 32; j++) {
            float oj = qh[p][j];
            const float* wrow = woutT + (long)(hh * 32 + j) * 128;
#pragma unroll
            for (int i = 0; i < 128; i++) x[i] += oj * wrow[i];
        }
    }
#pragma unroll
    for (int i = 0; i < 128; i++) x[i] += bout[i];

    // FFN: x += relu(LN2(x) @ W1^T + b1) @ W2^T + b2, fully fused per hidden j
    layernorm128(x, h, g2, b2v);
    for (int j = 0; j < 512; j++) {
        float t = dot128(h, W1 + (long)j * 128) + bf1[j];
        t = fmaxf(t, 0.f);
        const float* wrow = w2T + (long)j * 128;
#pragma unroll
        for (int i = 0; i < 128; i++) x[i] += t * wrow[i];
    }
#pragma unroll
    for (int i = 0; i < 128; i++) x[i] += bf2[i];

    // H_temp = LN(x0 + x) * tg + tb   (reload x0 from global)
#pragma unroll
    for (int d = 0; d < 128; d += 4) {
        float4 t = *(const float4*)(xrow + d);
        h[d] = x[d] + t.x; h[d+1] = x[d+1] + t.y; h[d+2] = x[d+2] + t.z; h[d+3] = x[d+3] + t.w;
    }
    layernorm128(h, h, tg, tbv);
    float* orow = Htemp + ((long)n * 128 + p) * 128;
#pragma unroll
    for (int d = 0; d < 128; d += 4) {
        float4 t; t.x = h[d]; t.y = h[d+1]; t.z = h[d+2]; t.w = h[d+3];
        *(float4*)(orow + d) = t;
    }
}

// ---------------------------------------------------------------------------
// Kernel 2: Hs = mean over Np of H_temp.  One thread per (n, d), coalesced.
__global__ void hs_kernel(const float* __restrict__ Htemp, float* __restrict__ Hs) {
    int idx = blockIdx.x * 256 + threadIdx.x;   // over B*C*D = 131072
    int n = idx >> 7, d = idx & 127;
    float s = 0.f;
    for (int p = 0; p < 128; p++) s += Htemp[((long)n * 128 + p) * 128 + d];
    Hs[idx] = s * 0.0078125f;
}

// ---------------------------------------------------------------------------
// Kernel 3: graph adjacency. One block per b. Computes q2/k2, sim, A =
// tanh(sim/8)+adj, stable top-8 per row, mask = top8 & ~eye & (A!=0),
// stored as a 64-bit row mask.
__global__ __launch_bounds__(256)
void graph_kernel(const float* __restrict__ Hs,
                  const float* __restrict__ qw, const float* __restrict__ qb,
                  const float* __restrict__ kw, const float* __restrict__ kb,
                  const float* __restrict__ adj, unsigned long long* __restrict__ masks) {
    __shared__ float q2l[64][65];
    __shared__ float k2l[64][65];
    __shared__ float am[64][65];
    int b = blockIdx.x;
    int tid = threadIdx.x;

    // q2/k2: 128 rows (64 q2 + 64 k2) x 64 cols; thread -> (r, jh)
    {
        int r = tid & 127, jh = tid >> 7;
        int row = r & 63;
        const float* wmat = (r < 64) ? qw : kw;
        const float* bvec = (r < 64) ? qb : kb;
        const float* src = Hs + (long)(b * 64 + row) * 128;
        for (int jj = 0; jj < 32; jj++) {
            int j = jh * 32 + jj;
            const float* wrow = wmat + (long)j * 128;
            float s0 = 0.f, s1 = 0.f, s2 = 0.f, s3 = 0.f;
#pragma unroll
            for (int d = 0; d < 128; d += 4) {
                s0 += src[d] * wrow[d];   s1 += src[d+1] * wrow[d+1];
                s2 += src[d+2] * wrow[d+2]; s3 += src[d+3] * wrow[d+3];
            }
            float val = ((s0 + s1) + (s2 + s3)) + bvec[j];
            if (r < 64) q2l[row][j] = val; else k2l[row][j] = val;
        }
    }
    __syncthreads();

    // sim + tanh + adj -> am
    {
        int c = tid & 63, eq = tid >> 6;
        for (int ee = 0; ee < 16; ee++) {
            int e = eq * 16 + ee;
            float s0 = 0.f, s1 = 0.f, s2 = 0.f, s3 = 0.f;
#pragma unroll
            for (int j = 0; j < 64; j += 4) {
                s0 += q2l[c][j]   * k2l[e][j];
                s1 += q2l[c][j+1] * k2l[e][j+1];
                s2 += q2l[c][j+2] * k2l[e][j+2];
                s3 += q2l[c][j+3] * k2l[e][j+3];
            }
            float sim = ((s0 + s1) + (s2 + s3)) * 0.125f;   // DK^-0.5, DK=64
            am[c][e] = tanhf(sim) + adj[c * 64 + e];
        }
    }
    __syncthreads();

    // top-8 per row (stable: strict > keeps earliest index on ties)
    if (tid < 64) {
        int c = tid;
        unsigned long long sel = 0ull;
        for (int it = 0; it < 8; it++) {
            float best = -1e38f; int bi = 0;
            for (int e = 0; e < 64; e++) {
                float v = am[c][e];
                bool ok = (((sel >> e) & 1ull) == 0ull) && (v > best);
                best = ok ? v : best;
                bi = ok ? e : bi;
            }
            sel |= (1ull << bi);
        }
        sel &= ~(1ull << c);                       // ~eye
        for (int e = 0; e < 64; e++)
            if (am[c][e] == 0.f) sel &= ~(1ull << e);   // (A != 0)
        masks[b * 64 + c] = sel;
    }
}

// ---------------------------------------------------------------------------
// Kernel 4: GAT + final LN. One block per (b,p). Per head: xh -> asrc/adst ->
// masked column-softmax over source s -> aggregate into per-thread registers.
// Then head-mean + bias + residual + LN, written over d_out in place.
__global__ __launch_bounds__(256)
void gat_kernel(float* __restrict__ Htemp,
                const float* __restrict__ gw,
                const float* __restrict__ asw, const float* __restrict__ adw,
                const float* __restrict__ gbias,
                const unsigned long long* __restrict__ masks,
                const float* __restrict__ sg, const float* __restrict__ sb) {
    __shared__ unsigned short Htb[64][130];   // H_temp tile, bf16
    __shared__ float xh[64][132];             // per-head xh, fp32, 16B-aligned rows
    __shared__ unsigned short attm[64][66];   // attention coeffs, bf16
    __shared__ float asrc_s[64], adst_s[64];
    __shared__ unsigned long long mk[64];
    __shared__ float stats[64][2];

    int bp = blockIdx.x;
    int b = bp >> 7, p = bp & 127;
    int tid = threadIdx.x;
    int lane = tid & 63, w = tid >> 6;

    // load H_temp[b, c, p, :] for all c
    {
        int c = tid >> 2, qq = tid & 3;
        const float* src = Htemp + ((long)(b * 64 + c) * 128 + p) * 128 + qq * 32;
#pragma unroll
        for (int k = 0; k < 8; k++) {
            float4 t = *(const float4*)(src + 4 * k);
            int f = qq * 32 + 4 * k;
            Htb[c][f]     = f2bf(t.x);
            Htb[c][f + 1] = f2bf(t.y);
            Htb[c][f + 2] = f2bf(t.z);
            Htb[c][f + 3] = f2bf(t.w);
        }
    }
    if (tid < 64) mk[tid] = masks[b * 64 + tid];
    __syncthreads();

    float oacc[32];
#pragma unroll
    for (int k = 0; k < 32; k++) oacc[k] = 0.f;

    for (int hh = 0; hh < 4; hh++) {
        // phase 1: xh[c][f] for this wave's 32 f's, 4 f at a time
        for (int fo = 0; fo < 32; fo += 4) {
            int f0 = w * 32 + fo;
            const float* wp = gw + ((long)(hh * 128 + f0)) * 128;
            float a0 = 0.f, a1 = 0.f, a2 = 0.f, a3 = 0.f;
#pragma unroll 8
            for (int d = 0; d < 128; d += 2) {
                unsigned int u = *(const unsigned int*)&Htb[lane][d];
                float h0 = __uint_as_float(u << 16);
                float h1 = __uint_as_float(u & 0xffff0000u);
                a0 += h0 * wp[d];       a0 += h1 * wp[d + 1];
                a1 += h0 * wp[128 + d]; a1 += h1 * wp[129 + d];
                a2 += h0 * wp[256 + d]; a2 += h1 * wp[257 + d];
                a3 += h0 * wp[384 + d]; a3 += h1 * wp[385 + d];
            }
            *(float4*)&xh[lane][f0] = make_float4(a0, a1, a2, a3);
        }
        __syncthreads();

        // phase 2: asrc / adst
        if (w == 0) {
            float s0 = 0.f, s1 = 0.f, s2 = 0.f, s3 = 0.f;
#pragma unroll
            for (int f = 0; f < 128; f += 4) {
                float4 xv = *(const float4*)&xh[lane][f];
                s0 += xv.x * asw[hh * 128 + f];
                s1 += xv.y * asw[hh * 128 + f + 1];
                s2 += xv.z * asw[hh * 128 + f + 2];
                s3 += xv.w * asw[hh * 128 + f + 3];
            }
            asrc_s[lane] = (s0 + s1) + (s2 + s3);
        } else if (w == 1) {
            float s0 = 0.f, s1 = 0.f, s2 = 0.f, s3 = 0.f;
#pragma unroll
            for (int f = 0; f < 128; f += 4) {
                float4 xv = *(const float4*)&xh[lane][f];
                s0 += xv.x * adw[hh * 128 + f];
                s1 += xv.y * adw[hh * 128 + f + 1];
                s2 += xv.z * adw[hh * 128 + f + 2];
                s3 += xv.w * adw[hh * 128 + f + 3];
            }
            adst_s[lane] = (s0 + s1) + (s2 + s3);
        }
        __syncthreads();

        // phase 3: masked softmax over source axis s, per target column t
        if (w == 0) {
            int t = lane;
            float ad = adst_s[t];
            float mmax = -1e30f;
            for (int s = 0; s < 64; s++) {
                float e = asrc_s[s] + ad; e = (e > 0.f) ? e : 0.2f * e;
                bool mb = (mk[s] >> t) & 1ull;
                mmax = mb ? fmaxf(mmax, e) : mmax;
            }
            float sum = 0.f;
            for (int s = 0; s < 64; s++) {
                float e = asrc_s[s] + ad; e = (e > 0.f) ? e : 0.2f * e;
                bool mb = (mk[s] >> t) & 1ull;
                float wv = mb ? __expf(e - mmax) : 0.f;
                sum += wv;
            }
            float rinv = (sum > 0.f) ? 1.f / sum : 0.f;
            for (int s = 0; s < 64; s++) {
                float e = asrc_s[s] + ad; e = (e > 0.f) ? e : 0.2f * e;
                bool mb = (mk[s] >> t) & 1ull;
                float wv = mb ? __expf(e - mmax) * rinv : 0.f;
                attm[s][t] = f2bf(wv);
            }
        }
        __syncthreads();

        // phase 4: out[t][f] += sum_s a[s][t] * xh[s][f]; lane = t, wave = f-chunk
        for (int s = 0; s < 64; s++) {
            float a = bf2f(attm[s][lane]);
            const float* xr = &xh[s][w * 32];
#pragma unroll
            for (int k = 0; k < 8; k++) {
                float4 xv = *(const float4*)(xr + 4 * k);
                oacc[4*k]   += a * xv.x;
                oacc[4*k+1] += a * xv.y;
                oacc[4*k+2] += a * xv.z;
                oacc[4*k+3] += a * xv.w;
            }
        }
        __syncthreads();   // before next head overwrites xh
    }

    // stage: head-mean + gat_bias + residual H_temp  (reuse xh buffer)
#pragma unroll
    for (int k = 0; k < 32; k++) {
        int f = w * 32 + k;
        xh[lane][f] = oacc[k] * 0.25f + gbias[f] + bf2f(Htb[lane][f]);
    }
    __syncthreads();

    // final LN stats per row
    if (w == 0) {
        int t = lane;
        float s0 = 0.f, s1 = 0.f, s2 = 0.f, s3 = 0.f;
#pragma unroll
        for (int f = 0; f < 128; f += 4) {
            float4 xv = *(const float4*)&xh[t][f];
            s0 += xv.x; s1 += xv.y; s2 += xv.z; s3 += xv.w;
        }
        float mu = ((s0 + s1) + (s2 + s3)) * 0.0078125f;
        s0 = s1 = s2 = s3 = 0.f;
#pragma unroll
        for (int f = 0; f < 128; f += 4) {
            float4 xv = *(const float4*)&xh[t][f];
            float a0 = xv.x - mu, a1 = xv.y - mu, a2 = xv.z - mu, a3 = xv.w - mu;
            s0 += a0 * a0; s1 += a1 * a1; s2 += a2 * a2; s3 += a3 * a3;
        }
        stats[t][0] = mu;
        stats[t][1] = rsqrtf(((s0 + s1) + (s2 + s3)) * 0.0078125f + 1e-5f);
    }
    __syncthreads();

    // apply LN + write y[b, c, p, :]  (overwrites H_temp rows only this block read)
    {
        int f = tid & 127, rh = tid >> 7;
        float sgv = sg[f], sbv = sb[f];
        for (int rb = 0; rb < 32; rb++) {
            int row = rb * 2 + rh;
            float val = (xh[row][f] - stats[row][0]) * stats[row][1] * sgv + sbv;
            Htemp[((long)(b * 64 + row) * 128 + p) * 128 + f] = val;
        }
    }
}

// ---------------------------------------------------------------------------
extern "C" void kernel_launch(void* const* d_in, const int* in_sizes, int n_in,
                              void* d_out, int out_size, void* d_ws, size_t ws_size,
                              hipStream_t stream) {
    const float* Hin        = (const float*)d_in[0];
    const float* static_adj = (const float*)d_in[1];
    const float* attn_in_w  = (const float*)d_in[2];
    const float* attn_in_b  = (const float*)d_in[3];
    const float* attn_out_w = (const float*)d_in[4];
    const float* attn_out_b = (const float*)d_in[5];
    const float* ln1_g      = (const float*)d_in[6];
    const float* ln1_b      = (const float*)d_in[7];
    const float* ln2_g      = (const float*)d_in[8];
    const float* ln2_b      = (const float*)d_in[9];
    const float* ff1_w      = (const float*)d_in[10];
    const float* ff1_b      = (const float*)d_in[11];
    const float* ff2_w      = (const float*)d_in[12];
    const float* ff2_b      = (const float*)d_in[13];
    const float* tnorm_g    = (const float*)d_in[14];
    const float* tnorm_b    = (const float*)d_in[15];
    const float* q_w        = (const float*)d_in[16];
    const float* q_b        = (const float*)d_in[17];
    const float* k_w        = (const float*)d_in[18];
    const float* k_b        = (const float*)d_in[19];
    const float* gat_w      = (const float*)d_in[20];
    const float* gat_att_src= (const float*)d_in[21];
    const float* gat_att_dst= (const float*)d_in[22];
    const float* gat_bias   = (const float*)d_in[23];
    const float* snorm_g    = (const float*)d_in[24];
    const float* snorm_b    = (const float*)d_in[25];

    float* out = (float*)d_out;   // doubles as H_temp scratch
    char* ws = (char*)d_ws;
    unsigned long long* masks = (unsigned long long*)ws;            // 8,192 B
    float* Hs    = (float*)(ws + 8192);                             // 524,288 B
    float* woutT = (float*)(ws + 8192 + 524288);                    // 65,536 B
    float* w2T   = (float*)(ws + 8192 + 524288 + 65536);            // 262,144 B

    hipLaunchKernelGGL(transpose_w_kernel, dim3(256), dim3(256), 0, stream,
                       attn_out_w, ff2_w, woutT, w2T);
    hipLaunchKernelGGL(temporal_kernel, dim3(1024), dim3(128), 0, stream,
                       Hin, attn_in_w, attn_in_b, woutT, attn_out_b,
                       ln1_g, ln1_b, ln2_g, ln2_b,
                       ff1_w, ff1_b, w2T, ff2_b, tnorm_g, tnorm_b, out);
    hipLaunchKernelGGL(hs_kernel, dim3(512), dim3(256), 0, stream, out, Hs);
    hipLaunchKernelGGL(graph_kernel, dim3(16), dim3(256), 0, stream,
                       Hs, q_w, q_b, k_w, k_b, static_adj, masks);
    hipLaunchKernelGGL(gat_kernel, dim3(2048), dim3(256), 0, stream,
                       out, gat_w, gat_att_src, gat_att_dst, gat_bias,
                       masks, snorm_g, snorm_b);
}

// Round 2
// 1723.456 us; speedup vs baseline: 3.8509x; 3.8509x over previous
//
#include <hip/hip_runtime.h>
#include <cstdint>

// B=16, C=64, Np=128, D=128, HT=4 (dh=32), HS=4, F=128, DK=64, TOPK=8

typedef __attribute__((ext_vector_type(8)))  short bf16x8;
typedef __attribute__((ext_vector_type(16))) float f32x16;
#define MFMA32(a, b, c) __builtin_amdgcn_mfma_f32_32x32x16_bf16((a), (b), (c), 0, 0, 0)

__device__ __forceinline__ unsigned short f2bf(float f) {
    unsigned int u = __float_as_uint(f);
    u += 0x7fffu + ((u >> 16) & 1u);
    return (unsigned short)(u >> 16);
}
__device__ __forceinline__ float bf2f(unsigned short u) {
    return __uint_as_float(((unsigned int)u) << 16);
}

// 8 consecutive bf16 from LDS (8B-aligned) -> MFMA A/B fragment
__device__ __forceinline__ bf16x8 lds_frag(const unsigned short* p) {
    union { bf16x8 v; ushort4 h[2]; } u;
    u.h[0] = *(const ushort4*)p;
    u.h[1] = *(const ushort4*)(p + 4);
    return u.v;
}

// C/D layout for 32x32x16: col = lane&31, row = (reg&3) + 8*(reg>>2) + 4*(lane>>5)
__device__ __forceinline__ int rowmap(int r, int hl) { return (r & 3) + 8 * (r >> 2) + 4 * hl; }

// ---------------------------------------------------------------------------
// Kernel: convert the 4 GEMM weight matrices to bf16, keeping [n][k] layout
// (k contiguous) which is exactly the MFMA B-fragment-friendly layout.
__global__ void wconv_kernel(const float* __restrict__ wqkv, const float* __restrict__ wout,
                             const float* __restrict__ w1, const float* __restrict__ w2,
                             unsigned short* __restrict__ dst) {
    int i = blockIdx.x * 256 + threadIdx.x;   // 196608 total
    float v;
    if (i < 49152)       v = wqkv[i];
    else if (i < 65536)  v = wout[i - 49152];
    else if (i < 131072) v = w1[i - 65536];
    else                 v = w2[i - 131072];
    dst[i] = f2bf(v);
}

// ---------------------------------------------------------------------------
// Kernel: LN1 + QKV + 4-head attention, one block per sequence n, 256 threads.
// O (128x128 bf16) written to upper half of d_out slot n.
__global__ __launch_bounds__(256, 1)
void seq_attn_kernel(const float* __restrict__ Hin,
                     const unsigned short* __restrict__ wqkv_b,
                     const float* __restrict__ bqkv,
                     const float* __restrict__ g1, const float* __restrict__ b1,
                     char* __restrict__ dout) {
    __shared__ unsigned short hb[128][132];     // LN1 output (A operand)
    __shared__ unsigned short qb[128][36];      // per-head q, row-major
    __shared__ unsigned short kb[128][36];      // per-head k, row-major (B of S)
    __shared__ unsigned short vT[32][132];      // per-head v transposed (B of O)
    __shared__ unsigned short Bst[3][32][132];  // staged weight cols for q/k/v
    __shared__ unsigned short Pb[4][32][132];   // per-wave P strips

    const int n = blockIdx.x;
    const int tid = threadIdx.x;
    const int lane = tid & 63;
    const int wv = tid >> 6;
    const int hl = lane >> 5;
    const int l31 = lane & 31;

    // ---- LN1: 2 threads per row ----
    {
        int row = tid >> 1, hf = tid & 1;
        const float* src = Hin + ((long)n * 128 + row) * 128 + hf * 64;
        float xv[64];
        float s = 0.f, qs = 0.f;
#pragma unroll
        for (int i = 0; i < 64; i += 4) {
            float4 t = *(const float4*)(src + i);
            xv[i] = t.x; xv[i+1] = t.y; xv[i+2] = t.z; xv[i+3] = t.w;
        }
#pragma unroll
        for (int i = 0; i < 64; i++) { s += xv[i]; qs += xv[i] * xv[i]; }
        s += __shfl_xor(s, 1); qs += __shfl_xor(qs, 1);
        float mu = s * 0.0078125f;
        float rs = rsqrtf(fmaxf(qs * 0.0078125f - mu * mu, 0.f) + 1e-5f);
#pragma unroll
        for (int i = 0; i < 64; i++) {
            int d = hf * 64 + i;
            hb[row][d] = f2bf((xv[i] - mu) * rs * g1[d] + b1[d]);
        }
    }
    __syncthreads();

    unsigned short* Optr = (unsigned short*)(dout + (long)n * 65536 + 32768);

    for (int h = 0; h < 4; h++) {
        // ---- stage B columns for q/k/v of this head ----
        for (int idx = tid; idx < 1536; idx += 256) {
            int mat = idx >> 9;
            int rem = idx & 511;
            int j = rem >> 4, kc = rem & 15;
            const unsigned short* s8 = wqkv_b + ((mat * 128 + h * 32 + j) * 128 + kc * 8);
            ushort4 lo = *(const ushort4*)s8, hi = *(const ushort4*)(s8 + 4);
            unsigned short* d8 = &Bst[mat][j][kc * 8];
            *(ushort4*)d8 = lo; *(ushort4*)(d8 + 4) = hi;
        }
        __syncthreads();

        // ---- q/k/v GEMMs for own 32-row strip ----
        {
            f32x16 accq, acck, accv;
            float bq = bqkv[      h * 32 + l31];
            float bk = bqkv[128 + h * 32 + l31];
            float bv = bqkv[256 + h * 32 + l31];
#pragma unroll
            for (int r = 0; r < 16; r++) { accq[r] = bq; acck[r] = bk; accv[r] = bv; }
#pragma unroll
            for (int k0 = 0; k0 < 128; k0 += 16) {
                bf16x8 a  = lds_frag(&hb[wv * 32 + l31][k0 + hl * 8]);
                bf16x8 b0 = lds_frag(&Bst[0][l31][k0 + hl * 8]);
                bf16x8 b1f = lds_frag(&Bst[1][l31][k0 + hl * 8]);
                bf16x8 b2f = lds_frag(&Bst[2][l31][k0 + hl * 8]);
                accq = MFMA32(a, b0, accq);
                acck = MFMA32(a, b1f, acck);
                accv = MFMA32(a, b2f, accv);
            }
#pragma unroll
            for (int r = 0; r < 16; r++) {
                int tok = wv * 32 + rowmap(r, hl);
                qb[tok][l31] = f2bf(accq[r]);
                kb[tok][l31] = f2bf(acck[r]);
                vT[l31][tok] = f2bf(accv[r]);
            }
        }
        __syncthreads();

        // ---- S = q k^T, softmax over keys ----
        f32x16 sacc[4];
#pragma unroll
        for (int t = 0; t < 4; t++)
#pragma unroll
            for (int r = 0; r < 16; r++) sacc[t][r] = 0.f;
#pragma unroll
        for (int k0 = 0; k0 < 32; k0 += 16) {
            bf16x8 a = lds_frag(&qb[wv * 32 + l31][k0 + hl * 8]);
#pragma unroll
            for (int t = 0; t < 4; t++) {
                bf16x8 b = lds_frag(&kb[t * 32 + l31][k0 + hl * 8]);
                sacc[t] = MFMA32(a, b, sacc[t]);
            }
        }
        const float scale = 0.17677669529663687f;   // 1/sqrt(32)
#pragma unroll
        for (int r = 0; r < 16; r++) {
            float m0 = fmaxf(fmaxf(sacc[0][r], sacc[1][r]), fmaxf(sacc[2][r], sacc[3][r]));
#pragma unroll
            for (int d = 1; d < 32; d <<= 1) m0 = fmaxf(m0, __shfl_xor(m0, d));
            float ssum = 0.f;
#pragma unroll
            for (int t = 0; t < 4; t++) {
                float e = __expf(scale * (sacc[t][r] - m0));
                sacc[t][r] = e; ssum += e;
            }
#pragma unroll
            for (int d = 1; d < 32; d <<= 1) ssum += __shfl_xor(ssum, d);
            float rinv = 1.f / ssum;
            int row = rowmap(r, hl);
#pragma unroll
            for (int t = 0; t < 4; t++)
                Pb[wv][row][t * 32 + l31] = f2bf(sacc[t][r] * rinv);
        }

        // ---- O = P @ v (own strip, no barrier needed: per-wave P strip) ----
        f32x16 oacc;
#pragma unroll
        for (int r = 0; r < 16; r++) oacc[r] = 0.f;
#pragma unroll
        for (int k0 = 0; k0 < 128; k0 += 16) {
            bf16x8 a = lds_frag(&Pb[wv][l31][k0 + hl * 8]);
            bf16x8 b = lds_frag(&vT[l31][k0 + hl * 8]);
            oacc = MFMA32(a, b, oacc);
        }
#pragma unroll
        for (int r = 0; r < 16; r++) {
            int tok = wv * 32 + rowmap(r, hl);
            Optr[tok * 128 + h * 32 + l31] = f2bf(oacc[r]);
        }
        __syncthreads();   // before next head overwrites Bst/qb/kb/vT
    }
}

// ---------------------------------------------------------------------------
// Kernel: attn-proj + residual + LN2 + FFN + residual + tnorm. One block per
// sequence. Writes fp32 H_temp into d_out slot n (overwriting the O region).
__global__ __launch_bounds__(256, 1)
void mlp_kernel(const float* __restrict__ Hin,
                const unsigned short* __restrict__ wout_b, const float* __restrict__ bout,
                const float* __restrict__ g2, const float* __restrict__ b2,
                const unsigned short* __restrict__ w1_b, const float* __restrict__ bf1,
                const unsigned short* __restrict__ w2_b, const float* __restrict__ bf2,
                const float* __restrict__ tg, const float* __restrict__ tb,
                char* __restrict__ dout) {
    __shared__ unsigned short Ab[128][132];    // O, later r-chunk
    __shared__ unsigned short h2b[128][132];
    __shared__ unsigned short BA[128][132];    // Wout, later B1 chunk
    __shared__ unsigned short BB[128][132];    // B2 chunk

    const int n = blockIdx.x;
    const int tid = threadIdx.x;
    const int lane = tid & 63;
    const int wv = tid >> 6;
    const int hl = lane >> 5;
    const int l31 = lane & 31;

    const unsigned short* Optr = (const unsigned short*)(dout + (long)n * 65536 + 32768);

    for (int idx = tid; idx < 2048; idx += 256) {
        int row = idx >> 4, kc = idx & 15;
        {
            const ushort4* s = (const ushort4*)(Optr + row * 128 + kc * 8);
            unsigned short* d = &Ab[row][kc * 8];
            *(ushort4*)d = s[0]; *(ushort4*)(d + 4) = s[1];
        }
        {
            const ushort4* s = (const ushort4*)(wout_b + row * 128 + kc * 8);
            unsigned short* d = &BA[row][kc * 8];
            *(ushort4*)d = s[0]; *(ushort4*)(d + 4) = s[1];
        }
    }
    __syncthreads();

    // ---- x = x0 + bout + O @ Wout^T ----
    f32x16 acc[4];
#pragma unroll
    for (int t = 0; t < 4; t++) {
        float bo = bout[t * 32 + l31];
#pragma unroll
        for (int r = 0; r < 16; r++) {
            int tok = wv * 32 + rowmap(r, hl);
            acc[t][r] = Hin[((long)n * 128 + tok) * 128 + t * 32 + l31] + bo;
        }
    }
#pragma unroll
    for (int k0 = 0; k0 < 128; k0 += 16) {
        bf16x8 a = lds_frag(&Ab[wv * 32 + l31][k0 + hl * 8]);
#pragma unroll
        for (int t = 0; t < 4; t++) {
            bf16x8 b = lds_frag(&BA[t * 32 + l31][k0 + hl * 8]);
            acc[t] = MFMA32(a, b, acc[t]);
        }
    }

    // ---- LN2 on C-layout fragments (32-lane shuffle reductions per row) ----
#pragma unroll
    for (int r = 0; r < 16; r++) {
        float s = acc[0][r] + acc[1][r] + acc[2][r] + acc[3][r];
#pragma unroll
        for (int d = 1; d < 32; d <<= 1) s += __shfl_xor(s, d);
        float mu = s * 0.0078125f;
        float q = 0.f;
#pragma unroll
        for (int t = 0; t < 4; t++) { float dv = acc[t][r] - mu; q += dv * dv; }
#pragma unroll
        for (int d = 1; d < 32; d <<= 1) q += __shfl_xor(q, d);
        float rs = rsqrtf(q * 0.0078125f + 1e-5f);
        int row = wv * 32 + rowmap(r, hl);
#pragma unroll
        for (int t = 0; t < 4; t++) {
            int col = t * 32 + l31;
            h2b[row][col] = f2bf((acc[t][r] - mu) * rs * g2[col] + b2[col]);
        }
    }

    // ---- acc2 = x + bf2; FFN in 4 K-chunks of 128 ----
    f32x16 acc2[4];
#pragma unroll
    for (int t = 0; t < 4; t++) {
        float bv = bf2[t * 32 + l31];
#pragma unroll
        for (int r = 0; r < 16; r++) acc2[t][r] = acc[t][r] + bv;
    }

    for (int j = 0; j < 4; j++) {
        __syncthreads();   // all waves done reading BA/BB/Ab from previous stage
        for (int idx = tid; idx < 2048; idx += 256) {
            int row = idx >> 4, kc = idx & 15;
            {
                const ushort4* s = (const ushort4*)(w1_b + ((j * 128 + row) * 128 + kc * 8));
                unsigned short* d = &BA[row][kc * 8];
                *(ushort4*)d = s[0]; *(ushort4*)(d + 4) = s[1];
            }
            {
                const ushort4* s = (const ushort4*)(w2_b + (row * 512 + j * 128 + kc * 8));
                unsigned short* d = &BB[row][kc * 8];
                *(ushort4*)d = s[0]; *(ushort4*)(d + 4) = s[1];
            }
        }
        __syncthreads();

        // r = relu(h2 @ B1c^T + b1c)
        f32x16 racc[4];
#pragma unroll
        for (int t = 0; t < 4; t++) {
            float bv = bf1[j * 128 + t * 32 + l31];
#pragma unroll
            for (int r = 0; r < 16; r++) racc[t][r] = bv;
        }
#pragma unroll
        for (int k0 = 0; k0 < 128; k0 += 16) {
            bf16x8 a = lds_frag(&h2b[wv * 32 + l31][k0 + hl * 8]);
#pragma unroll
            for (int t = 0; t < 4; t++) {
                bf16x8 b = lds_frag(&BA[t * 32 + l31][k0 + hl * 8]);
                racc[t] = MFMA32(a, b, racc[t]);
            }
        }
#pragma unroll
        for (int t = 0; t < 4; t++)
#pragma unroll
            for (int r = 0; r < 16; r++) {
                int row = wv * 32 + rowmap(r, hl);
                Ab[row][t * 32 + l31] = f2bf(fmaxf(racc[t][r], 0.f));
            }

        // acc2 += r @ B2c^T
#pragma unroll
        for (int k0 = 0; k0 < 128; k0 += 16) {
            bf16x8 a = lds_frag(&Ab[wv * 32 + l31][k0 + hl * 8]);
#pragma unroll
            for (int t = 0; t < 4; t++) {
                bf16x8 b = lds_frag(&BB[t * 32 + l31][k0 + hl * 8]);
                acc2[t] = MFMA32(a, b, acc2[t]);
            }
        }
    }

    // ---- H_temp = LN(x0 + x', tg, tb) -> fp32 d_out slot ----
#pragma unroll
    for (int t = 0; t < 4; t++)
#pragma unroll
        for (int r = 0; r < 16; r++) {
            int tok = wv * 32 + rowmap(r, hl);
            acc2[t][r] += Hin[((long)n * 128 + tok) * 128 + t * 32 + l31];
        }
    float* outf = (float*)dout + (long)n * 16384;
#pragma unroll
    for (int r = 0; r < 16; r++) {
        float s = acc2[0][r] + acc2[1][r] + acc2[2][r] + acc2[3][r];
#pragma unroll
        for (int d = 1; d < 32; d <<= 1) s += __shfl_xor(s, d);
        float mu = s * 0.0078125f;
        float q = 0.f;
#pragma unroll
        for (int t = 0; t < 4; t++) { float dv = acc2[t][r] - mu; q += dv * dv; }
#pragma unroll
        for (int d = 1; d < 32; d <<= 1) q += __shfl_xor(q, d);
        float rs = rsqrtf(q * 0.0078125f + 1e-5f);
        int tok = wv * 32 + rowmap(r, hl);
#pragma unroll
        for (int t = 0; t < 4; t++) {
            int col = t * 32 + l31;
            outf[tok * 128 + col] = (acc2[t][r] - mu) * rs * tg[col] + tb[col];
        }
    }
}

// ---------------------------------------------------------------------------
// Kernel: Hs = mean over Np of H_temp (coalesced).
__global__ void hs_kernel(const float* __restrict__ Htemp, float* __restrict__ Hs) {
    int idx = blockIdx.x * 256 + threadIdx.x;   // B*C*D = 131072
    int n = idx >> 7, d = idx & 127;
    float s = 0.f;
    for (int p = 0; p < 128; p++) s += Htemp[((long)n * 128 + p) * 128 + d];
    Hs[idx] = s * 0.0078125f;
}

// ---------------------------------------------------------------------------
// Kernel: graph adjacency (unchanged from R1 — passes).
__global__ __launch_bounds__(256)
void graph_kernel(const float* __restrict__ Hs,
                  const float* __restrict__ qw, const float* __restrict__ qb,
                  const float* __restrict__ kw, const float* __restrict__ kb,
                  const float* __restrict__ adj, unsigned long long* __restrict__ masks) {
    __shared__ float q2l[64][65];
    __shared__ float k2l[64][65];
    __shared__ float am[64][65];
    int b = blockIdx.x;
    int tid = threadIdx.x;
    {
        int r = tid & 127, jh = tid >> 7;
        int row = r & 63;
        const float* wmat = (r < 64) ? qw : kw;
        const float* bvec = (r < 64) ? qb : kb;
        const float* src = Hs + (long)(b * 64 + row) * 128;
        for (int jj = 0; jj < 32; jj++) {
            int j = jh * 32 + jj;
            const float* wrow = wmat + (long)j * 128;
            float s0 = 0.f, s1 = 0.f, s2 = 0.f, s3 = 0.f;
#pragma unroll
            for (int d = 0; d < 128; d += 4) {
                s0 += src[d] * wrow[d];     s1 += src[d+1] * wrow[d+1];
                s2 += src[d+2] * wrow[d+2]; s3 += src[d+3] * wrow[d+3];
            }
            float val = ((s0 + s1) + (s2 + s3)) + bvec[j];
            if (r < 64) q2l[row][j] = val; else k2l[row][j] = val;
        }
    }
    __syncthreads();
    {
        int c = tid & 63, eq = tid >> 6;
        for (int ee = 0; ee < 16; ee++) {
            int e = eq * 16 + ee;
            float s0 = 0.f, s1 = 0.f, s2 = 0.f, s3 = 0.f;
#pragma unroll
            for (int j = 0; j < 64; j += 4) {
                s0 += q2l[c][j]   * k2l[e][j];
                s1 += q2l[c][j+1] * k2l[e][j+1];
                s2 += q2l[c][j+2] * k2l[e][j+2];
                s3 += q2l[c][j+3] * k2l[e][j+3];
            }
            float sim = ((s0 + s1) + (s2 + s3)) * 0.125f;
            am[c][e] = tanhf(sim) + adj[c * 64 + e];
        }
    }
    __syncthreads();
    if (tid < 64) {
        int c = tid;
        unsigned long long sel = 0ull;
        for (int it = 0; it < 8; it++) {
            float best = -1e38f; int bi = 0;
            for (int e = 0; e < 64; e++) {
                float v = am[c][e];
                bool ok = (((sel >> e) & 1ull) == 0ull) && (v > best);
                best = ok ? v : best;
                bi = ok ? e : bi;
            }
            sel |= (1ull << bi);
        }
        sel &= ~(1ull << c);
        for (int e = 0; e < 64; e++)
            if (am[c][e] == 0.f) sel &= ~(1ull << e);
        masks[b * 64 + c] = sel;
    }
}

// ---------------------------------------------------------------------------
// Kernel: GAT + final LN (unchanged from R1 — passes).
__global__ __launch_bounds__(256)
void gat_kernel(float* __restrict__ Htemp,
                const float* __restrict__ gw,
                const float* __restrict__ asw, const float* __restrict__ adw,
                const float* __restrict__ gbias,
                const unsigned long long* __restrict__ masks,
                const float* __restrict__ sg, const float* __restrict__ sb) {
    __shared__ unsigned short Htb[64][130];
    __shared__ float xh[64][132];
    __shared__ unsigned short attm[64][66];
    __shared__ float asrc_s[64], adst_s[64];
    __shared__ unsigned long long mk[64];
    __shared__ float stats[64][2];

    int bp = blockIdx.x;
    int b = bp >> 7, p = bp & 127;
    int tid = threadIdx.x;
    int lane = tid & 63, w = tid >> 6;

    {
        int c = tid >> 2, qq = tid & 3;
        const float* src = Htemp + ((long)(b * 64 + c) * 128 + p) * 128 + qq * 32;
#pragma unroll
        for (int k = 0; k < 8; k++) {
            float4 t = *(const float4*)(src + 4 * k);
            int f = qq * 32 + 4 * k;
            Htb[c][f]     = f2bf(t.x);
            Htb[c][f + 1] = f2bf(t.y);
            Htb[c][f + 2] = f2bf(t.z);
            Htb[c][f + 3] = f2bf(t.w);
        }
    }
    if (tid < 64) mk[tid] = masks[b * 64 + tid];
    __syncthreads();

    float oacc[32];
#pragma unroll
    for (int k = 0; k < 32; k++) oacc[k] = 0.f;

    for (int hh = 0; hh < 4; hh++) {
        for (int fo = 0; fo < 32; fo += 4) {
            int f0 = w * 32 + fo;
            const float* wp = gw + ((long)(hh * 128 + f0)) * 128;
            float a0 = 0.f, a1 = 0.f, a2 = 0.f, a3 = 0.f;
#pragma unroll 8
            for (int d = 0; d < 128; d += 2) {
                unsigned int u = *(const unsigned int*)&Htb[lane][d];
                float h0 = __uint_as_float(u << 16);
                float h1 = __uint_as_float(u & 0xffff0000u);
                a0 += h0 * wp[d];       a0 += h1 * wp[d + 1];
                a1 += h0 * wp[128 + d]; a1 += h1 * wp[129 + d];
                a2 += h0 * wp[256 + d]; a2 += h1 * wp[257 + d];
                a3 += h0 * wp[384 + d]; a3 += h1 * wp[385 + d];
            }
            *(float4*)&xh[lane][f0] = make_float4(a0, a1, a2, a3);
        }
        __syncthreads();

        if (w == 0) {
            float s0 = 0.f, s1 = 0.f, s2 = 0.f, s3 = 0.f;
#pragma unroll
            for (int f = 0; f < 128; f += 4) {
                float4 xv = *(const float4*)&xh[lane][f];
                s0 += xv.x * asw[hh * 128 + f];
                s1 += xv.y * asw[hh * 128 + f + 1];
                s2 += xv.z * asw[hh * 128 + f + 2];
                s3 += xv.w * asw[hh * 128 + f + 3];
            }
            asrc_s[lane] = (s0 + s1) + (s2 + s3);
        } else if (w == 1) {
            float s0 = 0.f, s1 = 0.f, s2 = 0.f, s3 = 0.f;
#pragma unroll
            for (int f = 0; f < 128; f += 4) {
                float4 xv = *(const float4*)&xh[lane][f];
                s0 += xv.x * adw[hh * 128 + f];
                s1 += xv.y * adw[hh * 128 + f + 1];
                s2 += xv.z * adw[hh * 128 + f + 2];
                s3 += xv.w * adw[hh * 128 + f + 3];
            }
            adst_s[lane] = (s0 + s1) + (s2 + s3);
        }
        __syncthreads();

        if (w == 0) {
            int t = lane;
            float ad = adst_s[t];
            float mmax = -1e30f;
            for (int s = 0; s < 64; s++) {
                float e = asrc_s[s] + ad; e = (e > 0.f) ? e : 0.2f * e;
                bool mb = (mk[s] >> t) & 1ull;
                mmax = mb ? fmaxf(mmax, e) : mmax;
            }
            float sum = 0.f;
            for (int s = 0; s < 64; s++) {
                float e = asrc_s[s] + ad; e = (e > 0.f) ? e : 0.2f * e;
                bool mb = (mk[s] >> t) & 1ull;
                sum += mb ? __expf(e - mmax) : 0.f;
            }
            float rinv = (sum > 0.f) ? 1.f / sum : 0.f;
            for (int s = 0; s < 64; s++) {
                float e = asrc_s[s] + ad; e = (e > 0.f) ? e : 0.2f * e;
                bool mb = (mk[s] >> t) & 1ull;
                attm[s][t] = f2bf(mb ? __expf(e - mmax) * rinv : 0.f);
            }
        }
        __syncthreads();

        for (int s = 0; s < 64; s++) {
            float a = bf2f(attm[s][lane]);
            const float* xr = &xh[s][w * 32];
#pragma unroll
            for (int k = 0; k < 8; k++) {
                float4 xv = *(const float4*)(xr + 4 * k);
                oacc[4*k]   += a * xv.x;
                oacc[4*k+1] += a * xv.y;
                oacc[4*k+2] += a * xv.z;
                oacc[4*k+3] += a * xv.w;
            }
        }
        __syncthreads();
    }

#pragma unroll
    for (int k = 0; k < 32; k++) {
        int f = w * 32 + k;
        xh[lane][f] = oacc[k] * 0.25f + gbias[f] + bf2f(Htb[lane][f]);
    }
    __syncthreads();

    if (w == 0) {
        int t = lane;
        float s0 = 0.f, s1 = 0.f, s2 = 0.f, s3 = 0.f;
#pragma unroll
        for (int f = 0; f < 128; f += 4) {
            float4 xv = *(const float4*)&xh[t][f];
            s0 += xv.x; s1 += xv.y; s2 += xv.z; s3 += xv.w;
        }
        float mu = ((s0 + s1) + (s2 + s3)) * 0.0078125f;
        s0 = s1 = s2 = s3 = 0.f;
#pragma unroll
        for (int f = 0; f < 128; f += 4) {
            float4 xv = *(const float4*)&xh[t][f];
            float a0 = xv.x - mu, a1 = xv.y - mu, a2 = xv.z - mu, a3 = xv.w - mu;
            s0 += a0 * a0; s1 += a1 * a1; s2 += a2 * a2; s3 += a3 * a3;
        }
        stats[t][0] = mu;
        stats[t][1] = rsqrtf(((s0 + s1) + (s2 + s3)) * 0.0078125f + 1e-5f);
    }
    __syncthreads();

    {
        int f = tid & 127, rh = tid >> 7;
        float sgv = sg[f], sbv = sb[f];
        for (int rb = 0; rb < 32; rb++) {
            int row = rb * 2 + rh;
            float val = (xh[row][f] - stats[row][0]) * stats[row][1] * sgv + sbv;
            Htemp[((long)(b * 64 + row) * 128 + p) * 128 + f] = val;
        }
    }
}

// ---------------------------------------------------------------------------
extern "C" void kernel_launch(void* const* d_in, const int* in_sizes, int n_in,
                              void* d_out, int out_size, void* d_ws, size_t ws_size,
                              hipStream_t stream) {
    const float* Hin        = (const float*)d_in[0];
    const float* static_adj = (const float*)d_in[1];
    const float* attn_in_w  = (const float*)d_in[2];
    const float* attn_in_b  = (const float*)d_in[3];
    const float* attn_out_w = (const float*)d_in[4];
    const float* attn_out_b = (const float*)d_in[5];
    const float* ln1_g      = (const float*)d_in[6];
    const float* ln1_b      = (const float*)d_in[7];
    const float* ln2_g      = (const float*)d_in[8];
    const float* ln2_b      = (const float*)d_in[9];
    const float* ff1_w      = (const float*)d_in[10];
    const float* ff1_b      = (const float*)d_in[11];
    const float* ff2_w      = (const float*)d_in[12];
    const float* ff2_b      = (const float*)d_in[13];
    const float* tnorm_g    = (const float*)d_in[14];
    const float* tnorm_b    = (const float*)d_in[15];
    const float* q_w        = (const float*)d_in[16];
    const float* q_b        = (const float*)d_in[17];
    const float* k_w        = (const float*)d_in[18];
    const float* k_b        = (const float*)d_in[19];
    const float* gat_w      = (const float*)d_in[20];
    const float* gat_att_src= (const float*)d_in[21];
    const float* gat_att_dst= (const float*)d_in[22];
    const float* gat_bias   = (const float*)d_in[23];
    const float* snorm_g    = (const float*)d_in[24];
    const float* snorm_b    = (const float*)d_in[25];

    char* out = (char*)d_out;   // 1024 slots of 64 KiB: O (bf16) then H_temp (fp32)
    char* ws = (char*)d_ws;
    unsigned short* wb = (unsigned short*)ws;                 // 393216 B
    const unsigned short* wqkv_b = wb;
    const unsigned short* wout_b = wb + 49152;
    const unsigned short* w1_b   = wb + 65536;
    const unsigned short* w2_b   = wb + 131072;
    unsigned long long* masks = (unsigned long long*)(ws + 393216);   // 8192 B
    float* Hs = (float*)(ws + 401408);                                // 524288 B

    hipLaunchKernelGGL(wconv_kernel, dim3(768), dim3(256), 0, stream,
                       attn_in_w, attn_out_w, ff1_w, ff2_w, wb);
    hipLaunchKernelGGL(seq_attn_kernel, dim3(1024), dim3(256), 0, stream,
                       Hin, wqkv_b, attn_in_b, ln1_g, ln1_b, out);
    hipLaunchKernelGGL(mlp_kernel, dim3(1024), dim3(256), 0, stream,
                       Hin, wout_b, attn_out_b, ln2_g, ln2_b,
                       w1_b, ff1_b, w2_b, ff2_b, tnorm_g, tnorm_b, out);
    hipLaunchKernelGGL(hs_kernel, dim3(512), dim3(256), 0, stream, (float*)out, Hs);
    hipLaunchKernelGGL(graph_kernel, dim3(16), dim3(256), 0, stream,
                       Hs, q_w, q_b, k_w, k_b, static_adj, masks);
    hipLaunchKernelGGL(gat_kernel, dim3(2048), dim3(256), 0, stream,
                       (float*)out, gat_w, gat_att_src, gat_att_dst, gat_bias,
                       masks, snorm_g, snorm_b);
}

// Round 3
// 657.371 us; speedup vs baseline: 10.0961x; 2.6217x over previous
//
#include <hip/hip_runtime.h>
#include <cstdint>

// B=16, C=64, Np=128, D=128, HT=4 (dh=32), HS=4, F=128, DK=64, TOPK=8

typedef __attribute__((ext_vector_type(8)))  short bf16x8;
typedef __attribute__((ext_vector_type(16))) float f32x16;
#define MFMA32(a, b, c) __builtin_amdgcn_mfma_f32_32x32x16_bf16((a), (b), (c), 0, 0, 0)

__device__ __forceinline__ unsigned short f2bf(float f) {
    unsigned int u = __float_as_uint(f);
    u += 0x7fffu + ((u >> 16) & 1u);
    return (unsigned short)(u >> 16);
}
__device__ __forceinline__ float bf2f(unsigned short u) {
    return __uint_as_float(((unsigned int)u) << 16);
}

// 8 consecutive bf16 from LDS (8B-aligned) -> MFMA A/B fragment
__device__ __forceinline__ bf16x8 lds_frag(const unsigned short* p) {
    union { bf16x8 v; ushort4 h[2]; } u;
    u.h[0] = *(const ushort4*)p;
    u.h[1] = *(const ushort4*)(p + 4);
    return u.v;
}
// 8 consecutive bf16 from global (16B-aligned)
__device__ __forceinline__ bf16x8 gfrag(const unsigned short* p) {
    union { bf16x8 v; uint4 u; } t;
    t.u = *(const uint4*)p;
    return t.v;
}

// C/D layout for 32x32x16: col = lane&31, row = (reg&3) + 8*(reg>>2) + 4*(lane>>5)
__device__ __forceinline__ int rowmap(int r, int hl) { return (r & 3) + 8 * (r >> 2) + 4 * hl; }

// ---------------------------------------------------------------------------
// Convert the 5 GEMM weight matrices to bf16, keeping [n][k] layout.
__global__ void wconv_kernel(const float* __restrict__ wqkv, const float* __restrict__ wout,
                             const float* __restrict__ w1, const float* __restrict__ w2,
                             const float* __restrict__ gw,
                             unsigned short* __restrict__ dst) {
    int i = blockIdx.x * 256 + threadIdx.x;   // 262144 total
    float v;
    if (i < 49152)       v = wqkv[i];
    else if (i < 65536)  v = wout[i - 49152];
    else if (i < 131072) v = w1[i - 65536];
    else if (i < 196608) v = w2[i - 131072];
    else                 v = gw[i - 196608];
    dst[i] = f2bf(v);
}

// ---------------------------------------------------------------------------
// waS[h][d] = sum_f asw[h][f]*gw[h][f][d];  waD likewise with adw.  (fp32)
__global__ void wa_kernel(const float* __restrict__ gw, const float* __restrict__ asw,
                          const float* __restrict__ adw,
                          float* __restrict__ waS, float* __restrict__ waD) {
    int t = blockIdx.x * 256 + threadIdx.x;   // 1024
    int h = t >> 8, d = (t >> 1) & 127, which = t & 1;
    const float* av = which ? adw : asw;
    float s = 0.f;
    for (int f = 0; f < 128; f++) s += av[h * 128 + f] * gw[(h * 128 + f) * 128 + d];
    (which ? waD : waS)[h * 128 + d] = s;
}

// ---------------------------------------------------------------------------
// LN1 + QKV + 4-head attention, one block per sequence n, 256 threads.
__global__ __launch_bounds__(256, 1)
void seq_attn_kernel(const float* __restrict__ Hin,
                     const unsigned short* __restrict__ wqkv_b,
                     const float* __restrict__ bqkv,
                     const float* __restrict__ g1, const float* __restrict__ b1,
                     char* __restrict__ dout) {
    __shared__ unsigned short hb[128][132];
    __shared__ unsigned short qb[128][36];
    __shared__ unsigned short kb[128][36];
    __shared__ unsigned short vT[32][132];
    __shared__ unsigned short Bst[3][32][132];
    __shared__ unsigned short Pb[4][32][132];

    const int n = blockIdx.x;
    const int tid = threadIdx.x;
    const int lane = tid & 63;
    const int wv = tid >> 6;
    const int hl = lane >> 5;
    const int l31 = lane & 31;

    {
        int row = tid >> 1, hf = tid & 1;
        const float* src = Hin + ((long)n * 128 + row) * 128 + hf * 64;
        float xv[64];
        float s = 0.f, qs = 0.f;
#pragma unroll
        for (int i = 0; i < 64; i += 4) {
            float4 t = *(const float4*)(src + i);
            xv[i] = t.x; xv[i+1] = t.y; xv[i+2] = t.z; xv[i+3] = t.w;
        }
#pragma unroll
        for (int i = 0; i < 64; i++) { s += xv[i]; qs += xv[i] * xv[i]; }
        s += __shfl_xor(s, 1); qs += __shfl_xor(qs, 1);
        float mu = s * 0.0078125f;
        float rs = rsqrtf(fmaxf(qs * 0.0078125f - mu * mu, 0.f) + 1e-5f);
#pragma unroll
        for (int i = 0; i < 64; i++) {
            int d = hf * 64 + i;
            hb[row][d] = f2bf((xv[i] - mu) * rs * g1[d] + b1[d]);
        }
    }
    __syncthreads();

    unsigned short* Optr = (unsigned short*)(dout + (long)n * 65536 + 32768);

    for (int h = 0; h < 4; h++) {
        for (int idx = tid; idx < 1536; idx += 256) {
            int mat = idx >> 9;
            int rem = idx & 511;
            int j = rem >> 4, kc = rem & 15;
            const unsigned short* s8 = wqkv_b + ((mat * 128 + h * 32 + j) * 128 + kc * 8);
            ushort4 lo = *(const ushort4*)s8, hi = *(const ushort4*)(s8 + 4);
            unsigned short* d8 = &Bst[mat][j][kc * 8];
            *(ushort4*)d8 = lo; *(ushort4*)(d8 + 4) = hi;
        }
        __syncthreads();

        {
            f32x16 accq, acck, accv;
            float bq = bqkv[      h * 32 + l31];
            float bk = bqkv[128 + h * 32 + l31];
            float bv = bqkv[256 + h * 32 + l31];
#pragma unroll
            for (int r = 0; r < 16; r++) { accq[r] = bq; acck[r] = bk; accv[r] = bv; }
#pragma unroll
            for (int k0 = 0; k0 < 128; k0 += 16) {
                bf16x8 a  = lds_frag(&hb[wv * 32 + l31][k0 + hl * 8]);
                bf16x8 b0 = lds_frag(&Bst[0][l31][k0 + hl * 8]);
                bf16x8 b1f = lds_frag(&Bst[1][l31][k0 + hl * 8]);
                bf16x8 b2f = lds_frag(&Bst[2][l31][k0 + hl * 8]);
                accq = MFMA32(a, b0, accq);
                acck = MFMA32(a, b1f, acck);
                accv = MFMA32(a, b2f, accv);
            }
#pragma unroll
            for (int r = 0; r < 16; r++) {
                int tok = wv * 32 + rowmap(r, hl);
                qb[tok][l31] = f2bf(accq[r]);
                kb[tok][l31] = f2bf(acck[r]);
                vT[l31][tok] = f2bf(accv[r]);
            }
        }
        __syncthreads();

        f32x16 sacc[4];
#pragma unroll
        for (int t = 0; t < 4; t++)
#pragma unroll
            for (int r = 0; r < 16; r++) sacc[t][r] = 0.f;
#pragma unroll
        for (int k0 = 0; k0 < 32; k0 += 16) {
            bf16x8 a = lds_frag(&qb[wv * 32 + l31][k0 + hl * 8]);
#pragma unroll
            for (int t = 0; t < 4; t++) {
                bf16x8 b = lds_frag(&kb[t * 32 + l31][k0 + hl * 8]);
                sacc[t] = MFMA32(a, b, sacc[t]);
            }
        }
        const float scale = 0.17677669529663687f;
#pragma unroll
        for (int r = 0; r < 16; r++) {
            float m0 = fmaxf(fmaxf(sacc[0][r], sacc[1][r]), fmaxf(sacc[2][r], sacc[3][r]));
#pragma unroll
            for (int d = 1; d < 32; d <<= 1) m0 = fmaxf(m0, __shfl_xor(m0, d));
            float ssum = 0.f;
#pragma unroll
            for (int t = 0; t < 4; t++) {
                float e = __expf(scale * (sacc[t][r] - m0));
                sacc[t][r] = e; ssum += e;
            }
#pragma unroll
            for (int d = 1; d < 32; d <<= 1) ssum += __shfl_xor(ssum, d);
            float rinv = 1.f / ssum;
            int row = rowmap(r, hl);
#pragma unroll
            for (int t = 0; t < 4; t++)
                Pb[wv][row][t * 32 + l31] = f2bf(sacc[t][r] * rinv);
        }

        f32x16 oacc;
#pragma unroll
        for (int r = 0; r < 16; r++) oacc[r] = 0.f;
#pragma unroll
        for (int k0 = 0; k0 < 128; k0 += 16) {
            bf16x8 a = lds_frag(&Pb[wv][l31][k0 + hl * 8]);
            bf16x8 b = lds_frag(&vT[l31][k0 + hl * 8]);
            oacc = MFMA32(a, b, oacc);
        }
#pragma unroll
        for (int r = 0; r < 16; r++) {
            int tok = wv * 32 + rowmap(r, hl);
            Optr[tok * 128 + h * 32 + l31] = f2bf(oacc[r]);
        }
        __syncthreads();
    }
}

// ---------------------------------------------------------------------------
// attn-proj + residual + LN2 + FFN + residual + tnorm. One block per sequence.
__global__ __launch_bounds__(256, 1)
void mlp_kernel(const float* __restrict__ Hin,
                const unsigned short* __restrict__ wout_b, const float* __restrict__ bout,
                const float* __restrict__ g2, const float* __restrict__ b2,
                const unsigned short* __restrict__ w1_b, const float* __restrict__ bf1,
                const unsigned short* __restrict__ w2_b, const float* __restrict__ bf2,
                const float* __restrict__ tg, const float* __restrict__ tb,
                char* __restrict__ dout) {
    __shared__ unsigned short Ab[128][132];
    __shared__ unsigned short h2b[128][132];
    __shared__ unsigned short BA[128][132];
    __shared__ unsigned short BB[128][132];

    const int n = blockIdx.x;
    const int tid = threadIdx.x;
    const int lane = tid & 63;
    const int wv = tid >> 6;
    const int hl = lane >> 5;
    const int l31 = lane & 31;

    const unsigned short* Optr = (const unsigned short*)(dout + (long)n * 65536 + 32768);

    for (int idx = tid; idx < 2048; idx += 256) {
        int row = idx >> 4, kc = idx & 15;
        {
            const ushort4* s = (const ushort4*)(Optr + row * 128 + kc * 8);
            unsigned short* d = &Ab[row][kc * 8];
            *(ushort4*)d = s[0]; *(ushort4*)(d + 4) = s[1];
        }
        {
            const ushort4* s = (const ushort4*)(wout_b + row * 128 + kc * 8);
            unsigned short* d = &BA[row][kc * 8];
            *(ushort4*)d = s[0]; *(ushort4*)(d + 4) = s[1];
        }
    }
    __syncthreads();

    f32x16 acc[4];
#pragma unroll
    for (int t = 0; t < 4; t++) {
        float bo = bout[t * 32 + l31];
#pragma unroll
        for (int r = 0; r < 16; r++) {
            int tok = wv * 32 + rowmap(r, hl);
            acc[t][r] = Hin[((long)n * 128 + tok) * 128 + t * 32 + l31] + bo;
        }
    }
#pragma unroll
    for (int k0 = 0; k0 < 128; k0 += 16) {
        bf16x8 a = lds_frag(&Ab[wv * 32 + l31][k0 + hl * 8]);
#pragma unroll
        for (int t = 0; t < 4; t++) {
            bf16x8 b = lds_frag(&BA[t * 32 + l31][k0 + hl * 8]);
            acc[t] = MFMA32(a, b, acc[t]);
        }
    }

#pragma unroll
    for (int r = 0; r < 16; r++) {
        float s = acc[0][r] + acc[1][r] + acc[2][r] + acc[3][r];
#pragma unroll
        for (int d = 1; d < 32; d <<= 1) s += __shfl_xor(s, d);
        float mu = s * 0.0078125f;
        float q = 0.f;
#pragma unroll
        for (int t = 0; t < 4; t++) { float dv = acc[t][r] - mu; q += dv * dv; }
#pragma unroll
        for (int d = 1; d < 32; d <<= 1) q += __shfl_xor(q, d);
        float rs = rsqrtf(q * 0.0078125f + 1e-5f);
        int row = wv * 32 + rowmap(r, hl);
#pragma unroll
        for (int t = 0; t < 4; t++) {
            int col = t * 32 + l31;
            h2b[row][col] = f2bf((acc[t][r] - mu) * rs * g2[col] + b2[col]);
        }
    }

    f32x16 acc2[4];
#pragma unroll
    for (int t = 0; t < 4; t++) {
        float bv = bf2[t * 32 + l31];
#pragma unroll
        for (int r = 0; r < 16; r++) acc2[t][r] = acc[t][r] + bv;
    }

    for (int j = 0; j < 4; j++) {
        __syncthreads();
        for (int idx = tid; idx < 2048; idx += 256) {
            int row = idx >> 4, kc = idx & 15;
            {
                const ushort4* s = (const ushort4*)(w1_b + ((j * 128 + row) * 128 + kc * 8));
                unsigned short* d = &BA[row][kc * 8];
                *(ushort4*)d = s[0]; *(ushort4*)(d + 4) = s[1];
            }
            {
                const ushort4* s = (const ushort4*)(w2_b + (row * 512 + j * 128 + kc * 8));
                unsigned short* d = &BB[row][kc * 8];
                *(ushort4*)d = s[0]; *(ushort4*)(d + 4) = s[1];
            }
        }
        __syncthreads();

        f32x16 racc[4];
#pragma unroll
        for (int t = 0; t < 4; t++) {
            float bv = bf1[j * 128 + t * 32 + l31];
#pragma unroll
            for (int r = 0; r < 16; r++) racc[t][r] = bv;
        }
#pragma unroll
        for (int k0 = 0; k0 < 128; k0 += 16) {
            bf16x8 a = lds_frag(&h2b[wv * 32 + l31][k0 + hl * 8]);
#pragma unroll
            for (int t = 0; t < 4; t++) {
                bf16x8 b = lds_frag(&BA[t * 32 + l31][k0 + hl * 8]);
                racc[t] = MFMA32(a, b, racc[t]);
            }
        }
#pragma unroll
        for (int t = 0; t < 4; t++)
#pragma unroll
            for (int r = 0; r < 16; r++) {
                int row = wv * 32 + rowmap(r, hl);
                Ab[row][t * 32 + l31] = f2bf(fmaxf(racc[t][r], 0.f));
            }

#pragma unroll
        for (int k0 = 0; k0 < 128; k0 += 16) {
            bf16x8 a = lds_frag(&Ab[wv * 32 + l31][k0 + hl * 8]);
#pragma unroll
            for (int t = 0; t < 4; t++) {
                bf16x8 b = lds_frag(&BB[t * 32 + l31][k0 + hl * 8]);
                acc2[t] = MFMA32(a, b, acc2[t]);
            }
        }
    }

#pragma unroll
    for (int t = 0; t < 4; t++)
#pragma unroll
        for (int r = 0; r < 16; r++) {
            int tok = wv * 32 + rowmap(r, hl);
            acc2[t][r] += Hin[((long)n * 128 + tok) * 128 + t * 32 + l31];
        }
    float* outf = (float*)dout + (long)n * 16384;
#pragma unroll
    for (int r = 0; r < 16; r++) {
        float s = acc2[0][r] + acc2[1][r] + acc2[2][r] + acc2[3][r];
#pragma unroll
        for (int d = 1; d < 32; d <<= 1) s += __shfl_xor(s, d);
        float mu = s * 0.0078125f;
        float q = 0.f;
#pragma unroll
        for (int t = 0; t < 4; t++) { float dv = acc2[t][r] - mu; q += dv * dv; }
#pragma unroll
        for (int d = 1; d < 32; d <<= 1) q += __shfl_xor(q, d);
        float rs = rsqrtf(q * 0.0078125f + 1e-5f);
        int tok = wv * 32 + rowmap(r, hl);
#pragma unroll
        for (int t = 0; t < 4; t++) {
            int col = t * 32 + l31;
            outf[tok * 128 + col] = (acc2[t][r] - mu) * rs * tg[col] + tb[col];
        }
    }
}

// ---------------------------------------------------------------------------
__global__ void hs_kernel(const float* __restrict__ Htemp, float* __restrict__ Hs) {
    int idx = blockIdx.x * 256 + threadIdx.x;
    int n = idx >> 7, d = idx & 127;
    float s = 0.f;
    for (int p = 0; p < 128; p++) s += Htemp[((long)n * 128 + p) * 128 + d];
    Hs[idx] = s * 0.0078125f;
}

// ---------------------------------------------------------------------------
__global__ __launch_bounds__(256)
void graph_kernel(const float* __restrict__ Hs,
                  const float* __restrict__ qw, const float* __restrict__ qb,
                  const float* __restrict__ kw, const float* __restrict__ kb,
                  const float* __restrict__ adj, unsigned long long* __restrict__ masks) {
    __shared__ float q2l[64][65];
    __shared__ float k2l[64][65];
    __shared__ float am[64][65];
    int b = blockIdx.x;
    int tid = threadIdx.x;
    {
        int r = tid & 127, jh = tid >> 7;
        int row = r & 63;
        const float* wmat = (r < 64) ? qw : kw;
        const float* bvec = (r < 64) ? qb : kb;
        const float* src = Hs + (long)(b * 64 + row) * 128;
        for (int jj = 0; jj < 32; jj++) {
            int j = jh * 32 + jj;
            const float* wrow = wmat + (long)j * 128;
            float s0 = 0.f, s1 = 0.f, s2 = 0.f, s3 = 0.f;
#pragma unroll
            for (int d = 0; d < 128; d += 4) {
                s0 += src[d] * wrow[d];     s1 += src[d+1] * wrow[d+1];
                s2 += src[d+2] * wrow[d+2]; s3 += src[d+3] * wrow[d+3];
            }
            float val = ((s0 + s1) + (s2 + s3)) + bvec[j];
            if (r < 64) q2l[row][j] = val; else k2l[row][j] = val;
        }
    }
    __syncthreads();
    {
        int c = tid & 63, eq = tid >> 6;
        for (int ee = 0; ee < 16; ee++) {
            int e = eq * 16 + ee;
            float s0 = 0.f, s1 = 0.f, s2 = 0.f, s3 = 0.f;
#pragma unroll
            for (int j = 0; j < 64; j += 4) {
                s0 += q2l[c][j]   * k2l[e][j];
                s1 += q2l[c][j+1] * k2l[e][j+1];
                s2 += q2l[c][j+2] * k2l[e][j+2];
                s3 += q2l[c][j+3] * k2l[e][j+3];
            }
            float sim = ((s0 + s1) + (s2 + s3)) * 0.125f;
            am[c][e] = tanhf(sim) + adj[c * 64 + e];
        }
    }
    __syncthreads();
    if (tid < 64) {
        int c = tid;
        unsigned long long sel = 0ull;
        for (int it = 0; it < 8; it++) {
            float best = -1e38f; int bi = 0;
            for (int e = 0; e < 64; e++) {
                float v = am[c][e];
                bool ok = (((sel >> e) & 1ull) == 0ull) && (v > best);
                best = ok ? v : best;
                bi = ok ? e : bi;
            }
            sel |= (1ull << bi);
        }
        sel &= ~(1ull << c);
        for (int e = 0; e < 64; e++)
            if (am[c][e] == 0.f) sel &= ~(1ull << e);
        masks[b * 64 + c] = sel;
    }
}

// ---------------------------------------------------------------------------
// GAT + final LN, MFMA version. One block per (b,p), 256 threads (4 waves).
// Wave tile: rows rs=(wv&1)*32 (c/s/t), cols cs=(wv>>1)*64 (f).
__global__ __launch_bounds__(256, 1)
void gat_kernel(float* __restrict__ Htemp,
                const unsigned short* __restrict__ gwb,
                const float* __restrict__ waS, const float* __restrict__ waD,
                const float* __restrict__ gbias,
                const unsigned long long* __restrict__ masks,
                const float* __restrict__ sg, const float* __restrict__ sb) {
    __shared__ unsigned short Htb[64][132];   // A: H_temp (c, d) bf16
    __shared__ double ovl_d[3264];            // xhT[128][68] + attT[64][68]; part[] overlays
    __shared__ float asrcF[4][64], adstF[4][64];
    __shared__ float pmax[4][64], psum[4][64];   // softmax partials; reused for final LN
    __shared__ unsigned long long mk[64];

    unsigned short (*xhT)[68]  = (unsigned short(*)[68])ovl_d;                    // [f][s]
    unsigned short (*attT)[68] = (unsigned short(*)[68])((char*)ovl_d + 17408);   // [t][s]
    float (*part)[8][64]       = (float(*)[8][64])ovl_d;                          // pre-loop only

    const int bp = blockIdx.x;
    const int b = bp >> 7, p = bp & 127;
    const int tid = threadIdx.x;
    const int lane = tid & 63, wv = tid >> 6;
    const int hl = lane >> 5, l31 = lane & 31;
    const int rs = (wv & 1) * 32;
    const int cs = (wv >> 1) * 64;

    // load H_temp[b, c, p, :] -> bf16 Htb
    {
        int c = tid >> 2, qq = tid & 3;
        const float* src = Htemp + ((long)(b * 64 + c) * 128 + p) * 128 + qq * 32;
#pragma unroll
        for (int k = 0; k < 8; k++) {
            float4 t4 = *(const float4*)(src + 4 * k);
            ushort4 u; u.x = f2bf(t4.x); u.y = f2bf(t4.y); u.z = f2bf(t4.z); u.w = f2bf(t4.w);
            *(ushort4*)&Htb[c][qq * 32 + 4 * k] = u;
        }
    }
    if (tid < 64) mk[tid] = masks[b * 64 + tid];
    __syncthreads();

    // asrc/adst for all heads at once: asrc[h][s] = Htb[s,:] . waS[h,:]
    {
        int s = lane, q = wv;   // q is wave-uniform -> waS/waD reads are scalar
        float acc[8];
#pragma unroll
        for (int m = 0; m < 8; m++) acc[m] = 0.f;
        const unsigned int* hp = (const unsigned int*)&Htb[s][q * 32];
#pragma unroll
        for (int d2 = 0; d2 < 16; d2++) {
            unsigned int u = hp[d2];
            float f0 = __uint_as_float(u << 16);
            float f1 = __uint_as_float(u & 0xffff0000u);
            int d = q * 32 + 2 * d2;
#pragma unroll
            for (int h = 0; h < 4; h++) {
                acc[2*h]   += f0 * waS[h * 128 + d] + f1 * waS[h * 128 + d + 1];
                acc[2*h+1] += f0 * waD[h * 128 + d] + f1 * waD[h * 128 + d + 1];
            }
        }
#pragma unroll
        for (int m = 0; m < 8; m++) part[q][m][s] = acc[m];
    }
    __syncthreads();
    for (int o = tid; o < 512; o += 256) {
        int h = o >> 7, rem = o & 127, which = rem >> 6, s = rem & 63;
        int m = h * 2 + which;
        float v = part[0][m][s] + part[1][m][s] + part[2][m][s] + part[3][m][s];
        if (which == 0) asrcF[h][s] = v; else adstF[h][s] = v;
    }
    __syncthreads();   // also: part dead before xhT writes begin

    f32x16 oacc0, oacc1;
#pragma unroll
    for (int r = 0; r < 16; r++) { oacc0[r] = 0.f; oacc1[r] = 0.f; }

    for (int h = 0; h < 4; h++) {
        // ---- phase 1: xh = Htb @ gw^T (B fragments straight from global) ----
        f32x16 a0, a1;
#pragma unroll
        for (int r = 0; r < 16; r++) { a0[r] = 0.f; a1[r] = 0.f; }
        const unsigned short* gwh = gwb + h * 16384;
#pragma unroll
        for (int k0 = 0; k0 < 128; k0 += 16) {
            bf16x8 af = lds_frag(&Htb[rs + l31][k0 + hl * 8]);
            bf16x8 b0 = gfrag(gwh + (cs + l31) * 128 + k0 + hl * 8);
            bf16x8 b1 = gfrag(gwh + (cs + 32 + l31) * 128 + k0 + hl * 8);
            a0 = MFMA32(af, b0, a0);
            a1 = MFMA32(af, b1, a1);
        }
        // write transposed into xhT[f][s] (B layout for phase 4)
#pragma unroll
        for (int g = 0; g < 4; g++) {
            ushort4 u0, u1;
            u0.x = f2bf(a0[4*g]);   u0.y = f2bf(a0[4*g+1]);
            u0.z = f2bf(a0[4*g+2]); u0.w = f2bf(a0[4*g+3]);
            u1.x = f2bf(a1[4*g]);   u1.y = f2bf(a1[4*g+1]);
            u1.z = f2bf(a1[4*g+2]); u1.w = f2bf(a1[4*g+3]);
            int so = rs + 4 * hl + 8 * g;
            *(ushort4*)&xhT[cs + l31][so]      = u0;
            *(ushort4*)&xhT[cs + 32 + l31][so] = u1;
        }
        __syncthreads();

        // ---- masked column-softmax: t = lane, s-quarter = wv ----
        {
            int t = lane;
            float adv = adstF[h][t];
            float ev[16];
            float mx = -1e30f;
#pragma unroll
            for (int i = 0; i < 16; i++) {
                int s = wv * 16 + i;
                float e = asrcF[h][s] + adv;
                e = (e > 0.f) ? e : 0.2f * e;
                ev[i] = e;
                if ((mk[s] >> t) & 1ull) mx = fmaxf(mx, e);
            }
            pmax[wv][t] = mx;
            __syncthreads();
            float M = fmaxf(fmaxf(pmax[0][t], pmax[1][t]), fmaxf(pmax[2][t], pmax[3][t]));
            float sm = 0.f;
#pragma unroll
            for (int i = 0; i < 16; i++) {
                int s = wv * 16 + i;
                float w = ((mk[s] >> t) & 1ull) ? __expf(ev[i] - M) : 0.f;
                ev[i] = w; sm += w;
            }
            psum[wv][t] = sm;
            __syncthreads();
            float S = psum[0][t] + psum[1][t] + psum[2][t] + psum[3][t];
            float rinv = (S > 0.f) ? 1.f / S : 0.f;
#pragma unroll
            for (int g = 0; g < 4; g++) {
                ushort4 u;
                u.x = f2bf(ev[4*g]   * rinv); u.y = f2bf(ev[4*g+1] * rinv);
                u.z = f2bf(ev[4*g+2] * rinv); u.w = f2bf(ev[4*g+3] * rinv);
                *(ushort4*)&attT[t][wv * 16 + 4 * g] = u;
            }
        }
        __syncthreads();

        // ---- phase 4: out += a^T @ xh (A = attT[t][s], B = xhT[f][s]) ----
#pragma unroll
        for (int k0 = 0; k0 < 64; k0 += 16) {
            bf16x8 af = lds_frag(&attT[rs + l31][k0 + hl * 8]);
            bf16x8 b0 = lds_frag(&xhT[cs + l31][k0 + hl * 8]);
            bf16x8 b1 = lds_frag(&xhT[cs + 32 + l31][k0 + hl * 8]);
            oacc0 = MFMA32(af, b0, oacc0);
            oacc1 = MFMA32(af, b1, oacc1);
        }
        __syncthreads();   // before next head overwrites xhT/attT/pmax/psum
    }

    // ---- epilogue: head-mean + bias + residual, LN over f, store ----
    float gb0 = gbias[cs + l31], gb1 = gbias[cs + 32 + l31];
    float v0[16], v1[16];
#pragma unroll
    for (int r = 0; r < 16; r++) {
        int c = rs + rowmap(r, hl);
        v0[r] = oacc0[r] * 0.25f + gb0 + bf2f(Htb[c][cs + l31]);
        v1[r] = oacc1[r] * 0.25f + gb1 + bf2f(Htb[c][cs + 32 + l31]);
    }
#pragma unroll
    for (int r = 0; r < 16; r++) {
        float s = v0[r] + v1[r];
        float q = v0[r] * v0[r] + v1[r] * v1[r];
#pragma unroll
        for (int d = 1; d < 32; d <<= 1) { s += __shfl_xor(s, d); q += __shfl_xor(q, d); }
        if (l31 == 0) {
            int c = rs + rowmap(r, hl);
            pmax[wv >> 1][c] = s;    // row-sum partial (this wave's 64 cols)
            psum[wv >> 1][c] = q;    // row-sumsq partial
        }
    }
    __syncthreads();
    float sgv0 = sg[cs + l31], sbv0 = sb[cs + l31];
    float sgv1 = sg[cs + 32 + l31], sbv1 = sb[cs + 32 + l31];
#pragma unroll
    for (int r = 0; r < 16; r++) {
        int c = rs + rowmap(r, hl);
        float sum = pmax[0][c] + pmax[1][c];
        float sq  = psum[0][c] + psum[1][c];
        float mu = sum * 0.0078125f;
        float var = sq * 0.0078125f - mu * mu;
        float rsd = rsqrtf(fmaxf(var, 0.f) + 1e-5f);
        float* orow = Htemp + ((long)(b * 64 + c) * 128 + p) * 128;
        orow[cs + l31]      = (v0[r] - mu) * rsd * sgv0 + sbv0;
        orow[cs + 32 + l31] = (v1[r] - mu) * rsd * sgv1 + sbv1;
    }
}

// ---------------------------------------------------------------------------
extern "C" void kernel_launch(void* const* d_in, const int* in_sizes, int n_in,
                              void* d_out, int out_size, void* d_ws, size_t ws_size,
                              hipStream_t stream) {
    const float* Hin        = (const float*)d_in[0];
    const float* static_adj = (const float*)d_in[1];
    const float* attn_in_w  = (const float*)d_in[2];
    const float* attn_in_b  = (const float*)d_in[3];
    const float* attn_out_w = (const float*)d_in[4];
    const float* attn_out_b = (const float*)d_in[5];
    const float* ln1_g      = (const float*)d_in[6];
    const float* ln1_b      = (const float*)d_in[7];
    const float* ln2_g      = (const float*)d_in[8];
    const float* ln2_b      = (const float*)d_in[9];
    const float* ff1_w      = (const float*)d_in[10];
    const float* ff1_b      = (const float*)d_in[11];
    const float* ff2_w      = (const float*)d_in[12];
    const float* ff2_b      = (const float*)d_in[13];
    const float* tnorm_g    = (const float*)d_in[14];
    const float* tnorm_b    = (const float*)d_in[15];
    const float* q_w        = (const float*)d_in[16];
    const float* q_b        = (const float*)d_in[17];
    const float* k_w        = (const float*)d_in[18];
    const float* k_b        = (const float*)d_in[19];
    const float* gat_w      = (const float*)d_in[20];
    const float* gat_att_src= (const float*)d_in[21];
    const float* gat_att_dst= (const float*)d_in[22];
    const float* gat_bias   = (const float*)d_in[23];
    const float* snorm_g    = (const float*)d_in[24];
    const float* snorm_b    = (const float*)d_in[25];

    char* out = (char*)d_out;   // 1024 slots of 64 KiB: H_temp fp32 (lower) + O bf16 (upper)
    char* ws = (char*)d_ws;
    unsigned short* wb = (unsigned short*)ws;                 // 524288 B (bf16 weights)
    const unsigned short* wqkv_b = wb;
    const unsigned short* wout_b = wb + 49152;
    const unsigned short* w1_b   = wb + 65536;
    const unsigned short* w2_b   = wb + 131072;
    const unsigned short* gw_b   = wb + 196608;
    unsigned long long* masks = (unsigned long long*)(ws + 524288);   // 8192 B
    float* Hs  = (float*)(ws + 532480);                               // 524288 B
    float* waS = (float*)(ws + 1056768);                              // 2048 B
    float* waD = (float*)(ws + 1058816);                              // 2048 B

    hipLaunchKernelGGL(wconv_kernel, dim3(1024), dim3(256), 0, stream,
                       attn_in_w, attn_out_w, ff1_w, ff2_w, gat_w, wb);
    hipLaunchKernelGGL(wa_kernel, dim3(4), dim3(256), 0, stream,
                       gat_w, gat_att_src, gat_att_dst, waS, waD);
    hipLaunchKernelGGL(seq_attn_kernel, dim3(1024), dim3(256), 0, stream,
                       Hin, wqkv_b, attn_in_b, ln1_g, ln1_b, out);
    hipLaunchKernelGGL(mlp_kernel, dim3(1024), dim3(256), 0, stream,
                       Hin, wout_b, attn_out_b, ln2_g, ln2_b,
                       w1_b, ff1_b, w2_b, ff2_b, tnorm_g, tnorm_b, out);
    hipLaunchKernelGGL(hs_kernel, dim3(512), dim3(256), 0, stream, (float*)out, Hs);
    hipLaunchKernelGGL(graph_kernel, dim3(16), dim3(256), 0, stream,
                       Hs, q_w, q_b, k_w, k_b, static_adj, masks);
    hipLaunchKernelGGL(gat_kernel, dim3(2048), dim3(256), 0, stream,
                       (float*)out, gw_b, waS, waD, gat_bias,
                       masks, snorm_g, snorm_b);
}

// Round 4
// 622.895 us; speedup vs baseline: 10.6549x; 1.0553x over previous
//
#include <hip/hip_runtime.h>
#include <cstdint>

// B=16, C=64, Np=128, D=128, HT=4 (dh=32), HS=4, F=128, DK=64, TOPK=8

typedef __attribute__((ext_vector_type(8)))  short bf16x8;
typedef __attribute__((ext_vector_type(16))) float f32x16;
#define MFMA32(a, b, c) __builtin_amdgcn_mfma_f32_32x32x16_bf16((a), (b), (c), 0, 0, 0)

__device__ __forceinline__ unsigned short f2bf(float f) {
    unsigned int u = __float_as_uint(f);
    u += 0x7fffu + ((u >> 16) & 1u);
    return (unsigned short)(u >> 16);
}
__device__ __forceinline__ float bf2f(unsigned short u) {
    return __uint_as_float(((unsigned int)u) << 16);
}

__device__ __forceinline__ bf16x8 lds_frag(const unsigned short* p) {
    union { bf16x8 v; ushort4 h[2]; } u;
    u.h[0] = *(const ushort4*)p;
    u.h[1] = *(const ushort4*)(p + 4);
    return u.v;
}
__device__ __forceinline__ bf16x8 gfrag(const unsigned short* p) {
    union { bf16x8 v; uint4 u; } t;
    t.u = *(const uint4*)p;
    return t.v;
}

// C/D layout for 32x32x16: col = lane&31, row = (reg&3) + 8*(reg>>2) + 4*(lane>>5)
__device__ __forceinline__ int rowmap(int r, int hl) { return (r & 3) + 8 * (r >> 2) + 4 * hl; }

// ---------------------------------------------------------------------------
__global__ void wconv_kernel(const float* __restrict__ wqkv, const float* __restrict__ wout,
                             const float* __restrict__ w1, const float* __restrict__ w2,
                             const float* __restrict__ gw,
                             unsigned short* __restrict__ dst) {
    int i = blockIdx.x * 256 + threadIdx.x;   // 262144 total
    float v;
    if (i < 49152)       v = wqkv[i];
    else if (i < 65536)  v = wout[i - 49152];
    else if (i < 131072) v = w1[i - 65536];
    else if (i < 196608) v = w2[i - 131072];
    else                 v = gw[i - 196608];
    dst[i] = f2bf(v);
}

// ---------------------------------------------------------------------------
__global__ void wa_kernel(const float* __restrict__ gw, const float* __restrict__ asw,
                          const float* __restrict__ adw,
                          float* __restrict__ waS, float* __restrict__ waD) {
    int t = blockIdx.x * 256 + threadIdx.x;   // 1024
    int h = t >> 8, d = (t >> 1) & 127, which = t & 1;
    const float* av = which ? adw : asw;
    float s = 0.f;
    for (int f = 0; f < 128; f++) s += av[h * 128 + f] * gw[(h * 128 + f) * 128 + d];
    (which ? waD : waS)[h * 128 + d] = s;
}

// ---------------------------------------------------------------------------
// Fused temporal block: LN1 + QKV + attention + proj + LN2 + FFN + tnorm.
// One block per sequence n, 256 threads (4 waves, 32-token strip each).
// LDS ~70 KB -> 2 blocks/CU. Weights streamed from global bf16 (L1/L2-hot).
__global__ __launch_bounds__(256, 2)
void temporal_kernel(const float* __restrict__ Hin,
                     const unsigned short* __restrict__ wqkv_b, const float* __restrict__ bqkv,
                     const unsigned short* __restrict__ wout_b, const float* __restrict__ bout,
                     const float* __restrict__ g1, const float* __restrict__ b1,
                     const float* __restrict__ g2, const float* __restrict__ b2,
                     const unsigned short* __restrict__ w1_b, const float* __restrict__ bf1,
                     const unsigned short* __restrict__ w2_b, const float* __restrict__ bf2,
                     const float* __restrict__ tg, const float* __restrict__ tb,
                     float* __restrict__ Htemp) {
    // Region A (33792 B): hb (LN1 out) -> O (attn output) -> relu activations
    __shared__ unsigned short RA[128][132];
    // Region B (36096 B): attn {qb,kb,vT,Pb} -> mlp {h2b}
    __shared__ double RBd[4512];
    unsigned short (*qb)[36]  = (unsigned short(*)[36])RBd;                       // [tok][dh]
    unsigned short (*kb)[36]  = (unsigned short(*)[36])((char*)RBd + 9216);       // [tok][dh]
    unsigned short (*vT)[132] = (unsigned short(*)[132])((char*)RBd + 18432);     // [d][tok]
    unsigned short (*Pb)[36]  = (unsigned short(*)[36])((char*)RBd + 26880);      // [wv*32+q][key-in-block]
    unsigned short (*h2b)[132] = (unsigned short(*)[132])RBd;                     // mlp phase

    const int n = blockIdx.x;
    const int tid = threadIdx.x;
    const int lane = tid & 63;
    const int wv = tid >> 6;
    const int hl = lane >> 5;
    const int l31 = lane & 31;
    const int myrow = wv * 32 + l31;

    // ---- LN1 (wave-private rows: tid>>1 maps wave w to rows w*32..w*32+31) ----
    {
        int row = tid >> 1, hf = tid & 1;
        const float* src = Hin + ((long)n * 128 + row) * 128 + hf * 64;
        float xv[64];
        float s = 0.f, qs = 0.f;
#pragma unroll
        for (int i = 0; i < 64; i += 4) {
            float4 t = *(const float4*)(src + i);
            xv[i] = t.x; xv[i+1] = t.y; xv[i+2] = t.z; xv[i+3] = t.w;
        }
#pragma unroll
        for (int i = 0; i < 64; i++) { s += xv[i]; qs += xv[i] * xv[i]; }
        s += __shfl_xor(s, 1); qs += __shfl_xor(qs, 1);
        float mu = s * 0.0078125f;
        float rs = rsqrtf(fmaxf(qs * 0.0078125f - mu * mu, 0.f) + 1e-5f);
#pragma unroll
        for (int i = 0; i < 64; i++) {
            int d = hf * 64 + i;
            RA[row][d] = f2bf((xv[i] - mu) * rs * g1[d] + b1[d]);
        }
    }
    // no barrier: RA rows are wave-private for QKV A-reads

    f32x16 oaccH[4];
#pragma unroll
    for (int h = 0; h < 4; h++)
#pragma unroll
        for (int r = 0; r < 16; r++) oaccH[h][r] = 0.f;

    for (int h = 0; h < 4; h++) {
        // ---- q/k/v GEMMs for own strip; B streamed from global ----
        {
            f32x16 accq, acck, accv;
            float bq = bqkv[      h * 32 + l31];
            float bk = bqkv[128 + h * 32 + l31];
            float bv = bqkv[256 + h * 32 + l31];
#pragma unroll
            for (int r = 0; r < 16; r++) { accq[r] = bq; acck[r] = bk; accv[r] = bv; }
            const unsigned short* wq = wqkv_b + (      h * 32 + l31) * 128 + hl * 8;
            const unsigned short* wk = wqkv_b + (128 + h * 32 + l31) * 128 + hl * 8;
            const unsigned short* wvp= wqkv_b + (256 + h * 32 + l31) * 128 + hl * 8;
#pragma unroll
            for (int k0 = 0; k0 < 128; k0 += 16) {
                bf16x8 a  = lds_frag(&RA[myrow][k0 + hl * 8]);
                accq = MFMA32(a, gfrag(wq + k0), accq);
                acck = MFMA32(a, gfrag(wk + k0), acck);
                accv = MFMA32(a, gfrag(wvp + k0), accv);
            }
#pragma unroll
            for (int r = 0; r < 16; r++) {
                int tok = wv * 32 + rowmap(r, hl);
                qb[tok][l31] = f2bf(accq[r]);
                kb[tok][l31] = f2bf(acck[r]);
                vT[l31][tok] = f2bf(accv[r]);
            }
        }
        __syncthreads();   // kb/vT are cross-wave

        // ---- S = q k^T (C: rows=own queries, cols=keys t*32+l31) ----
        f32x16 sacc[4];
#pragma unroll
        for (int t = 0; t < 4; t++)
#pragma unroll
            for (int r = 0; r < 16; r++) sacc[t][r] = 0.f;
#pragma unroll
        for (int k0 = 0; k0 < 32; k0 += 16) {
            bf16x8 a = lds_frag(&qb[myrow][k0 + hl * 8]);
#pragma unroll
            for (int t = 0; t < 4; t++) {
                bf16x8 b = lds_frag(&kb[t * 32 + l31][k0 + hl * 8]);
                sacc[t] = MFMA32(a, b, sacc[t]);
            }
        }
        const float scale = 0.17677669529663687f;   // 1/sqrt(32)
#pragma unroll
        for (int r = 0; r < 16; r++) {
            float m0 = fmaxf(fmaxf(sacc[0][r], sacc[1][r]), fmaxf(sacc[2][r], sacc[3][r]));
#pragma unroll
            for (int d = 1; d < 32; d <<= 1) m0 = fmaxf(m0, __shfl_xor(m0, d));
            float ssum = 0.f;
#pragma unroll
            for (int t = 0; t < 4; t++) {
                float e = __expf(scale * (sacc[t][r] - m0));
                sacc[t][r] = e; ssum += e;
            }
#pragma unroll
            for (int d = 1; d < 32; d <<= 1) ssum += __shfl_xor(ssum, d);
            float rinv = 1.f / ssum;
#pragma unroll
            for (int t = 0; t < 4; t++) sacc[t][r] *= rinv;
        }

        // ---- O += P@V per 32-key block through wave-private Pb strip ----
#pragma unroll
        for (int t = 0; t < 4; t++) {
#pragma unroll
            for (int r = 0; r < 16; r++)
                Pb[wv * 32 + rowmap(r, hl)][l31] = f2bf(sacc[t][r]);
#pragma unroll
            for (int k0 = 0; k0 < 32; k0 += 16) {
                bf16x8 a = lds_frag(&Pb[wv * 32 + l31][k0 + hl * 8]);
                bf16x8 b = lds_frag(&vT[l31][t * 32 + k0 + hl * 8]);
                oaccH[h] = MFMA32(a, b, oaccH[h]);
            }
        }
        __syncthreads();   // before next head overwrites kb/vT (and h2b overlay after loop)
    }

    // ---- O regs -> RA (hb dead; wave-private rows) ----
#pragma unroll
    for (int h = 0; h < 4; h++)
#pragma unroll
        for (int r = 0; r < 16; r++) {
            int tok = wv * 32 + rowmap(r, hl);
            RA[tok][h * 32 + l31] = f2bf(oaccH[h][r]);
        }

    // ---- x = x0 + bout + O @ Wout^T ----
    f32x16 acc[4];
#pragma unroll
    for (int t = 0; t < 4; t++) {
        float bo = bout[t * 32 + l31];
#pragma unroll
        for (int r = 0; r < 16; r++) {
            int tok = wv * 32 + rowmap(r, hl);
            acc[t][r] = Hin[((long)n * 128 + tok) * 128 + t * 32 + l31] + bo;
        }
    }
#pragma unroll
    for (int k0 = 0; k0 < 128; k0 += 16) {
        bf16x8 a = lds_frag(&RA[myrow][k0 + hl * 8]);
#pragma unroll
        for (int t = 0; t < 4; t++) {
            bf16x8 b = gfrag(wout_b + (t * 32 + l31) * 128 + k0 + hl * 8);
            acc[t] = MFMA32(a, b, acc[t]);
        }
    }

    // ---- LN2 -> h2b (wave-private rows) ----
#pragma unroll
    for (int r = 0; r < 16; r++) {
        float s = acc[0][r] + acc[1][r] + acc[2][r] + acc[3][r];
#pragma unroll
        for (int d = 1; d < 32; d <<= 1) s += __shfl_xor(s, d);
        float mu = s * 0.0078125f;
        float q = 0.f;
#pragma unroll
        for (int t = 0; t < 4; t++) { float dv = acc[t][r] - mu; q += dv * dv; }
#pragma unroll
        for (int d = 1; d < 32; d <<= 1) q += __shfl_xor(q, d);
        float rs = rsqrtf(q * 0.0078125f + 1e-5f);
        int row = wv * 32 + rowmap(r, hl);
#pragma unroll
        for (int t = 0; t < 4; t++) {
            int col = t * 32 + l31;
            h2b[row][col] = f2bf((acc[t][r] - mu) * rs * g2[col] + b2[col]);
        }
    }

    f32x16 acc2[4];
#pragma unroll
    for (int t = 0; t < 4; t++) {
        float bv = bf2[t * 32 + l31];
#pragma unroll
        for (int r = 0; r < 16; r++) acc2[t][r] = acc[t][r] + bv;
    }

    // ---- FFN in 4 K-chunks of 128; relu strips through RA (wave-private) ----
    for (int j = 0; j < 4; j++) {
        f32x16 racc[4];
#pragma unroll
        for (int t = 0; t < 4; t++) {
            float bv = bf1[j * 128 + t * 32 + l31];
#pragma unroll
            for (int r = 0; r < 16; r++) racc[t][r] = bv;
        }
#pragma unroll
        for (int k0 = 0; k0 < 128; k0 += 16) {
            bf16x8 a = lds_frag(&h2b[myrow][k0 + hl * 8]);
#pragma unroll
            for (int t = 0; t < 4; t++) {
                bf16x8 b = gfrag(w1_b + (j * 128 + t * 32 + l31) * 128 + k0 + hl * 8);
                racc[t] = MFMA32(a, b, racc[t]);
            }
        }
#pragma unroll
        for (int t = 0; t < 4; t++)
#pragma unroll
            for (int r = 0; r < 16; r++) {
                int row = wv * 32 + rowmap(r, hl);
                RA[row][t * 32 + l31] = f2bf(fmaxf(racc[t][r], 0.f));
            }
#pragma unroll
        for (int k0 = 0; k0 < 128; k0 += 16) {
            bf16x8 a = lds_frag(&RA[myrow][k0 + hl * 8]);
#pragma unroll
            for (int t = 0; t < 4; t++) {
                bf16x8 b = gfrag(w2_b + (t * 32 + l31) * 512 + j * 128 + k0 + hl * 8);
                acc2[t] = MFMA32(a, b, acc2[t]);
            }
        }
    }

    // ---- H_temp = LN(x0 + x', tg, tb) ----
#pragma unroll
    for (int t = 0; t < 4; t++)
#pragma unroll
        for (int r = 0; r < 16; r++) {
            int tok = wv * 32 + rowmap(r, hl);
            acc2[t][r] += Hin[((long)n * 128 + tok) * 128 + t * 32 + l31];
        }
    float* outf = Htemp + (long)n * 16384;
#pragma unroll
    for (int r = 0; r < 16; r++) {
        float s = acc2[0][r] + acc2[1][r] + acc2[2][r] + acc2[3][r];
#pragma unroll
        for (int d = 1; d < 32; d <<= 1) s += __shfl_xor(s, d);
        float mu = s * 0.0078125f;
        float q = 0.f;
#pragma unroll
        for (int t = 0; t < 4; t++) { float dv = acc2[t][r] - mu; q += dv * dv; }
#pragma unroll
        for (int d = 1; d < 32; d <<= 1) q += __shfl_xor(q, d);
        float rs = rsqrtf(q * 0.0078125f + 1e-5f);
        int tok = wv * 32 + rowmap(r, hl);
#pragma unroll
        for (int t = 0; t < 4; t++) {
            int col = t * 32 + l31;
            outf[tok * 128 + col] = (acc2[t][r] - mu) * rs * tg[col] + tb[col];
        }
    }
}

// ---------------------------------------------------------------------------
__global__ void hs_kernel(const float* __restrict__ Htemp, float* __restrict__ Hs) {
    int idx = blockIdx.x * 256 + threadIdx.x;
    int n = idx >> 7, d = idx & 127;
    float s = 0.f;
    for (int p = 0; p < 128; p++) s += Htemp[((long)n * 128 + p) * 128 + d];
    Hs[idx] = s * 0.0078125f;
}

// ---------------------------------------------------------------------------
__global__ __launch_bounds__(256)
void graph_kernel(const float* __restrict__ Hs,
                  const float* __restrict__ qw, const float* __restrict__ qb,
                  const float* __restrict__ kw, const float* __restrict__ kb,
                  const float* __restrict__ adj, unsigned long long* __restrict__ masks) {
    __shared__ float q2l[64][65];
    __shared__ float k2l[64][65];
    __shared__ float am[64][65];
    int b = blockIdx.x;
    int tid = threadIdx.x;
    {
        int r = tid & 127, jh = tid >> 7;
        int row = r & 63;
        const float* wmat = (r < 64) ? qw : kw;
        const float* bvec = (r < 64) ? qb : kb;
        const float* src = Hs + (long)(b * 64 + row) * 128;
        for (int jj = 0; jj < 32; jj++) {
            int j = jh * 32 + jj;
            const float* wrow = wmat + (long)j * 128;
            float s0 = 0.f, s1 = 0.f, s2 = 0.f, s3 = 0.f;
#pragma unroll
            for (int d = 0; d < 128; d += 4) {
                s0 += src[d] * wrow[d];     s1 += src[d+1] * wrow[d+1];
                s2 += src[d+2] * wrow[d+2]; s3 += src[d+3] * wrow[d+3];
            }
            float val = ((s0 + s1) + (s2 + s3)) + bvec[j];
            if (r < 64) q2l[row][j] = val; else k2l[row][j] = val;
        }
    }
    __syncthreads();
    {
        int c = tid & 63, eq = tid >> 6;
        for (int ee = 0; ee < 16; ee++) {
            int e = eq * 16 + ee;
            float s0 = 0.f, s1 = 0.f, s2 = 0.f, s3 = 0.f;
#pragma unroll
            for (int j = 0; j < 64; j += 4) {
                s0 += q2l[c][j]   * k2l[e][j];
                s1 += q2l[c][j+1] * k2l[e][j+1];
                s2 += q2l[c][j+2] * k2l[e][j+2];
                s3 += q2l[c][j+3] * k2l[e][j+3];
            }
            float sim = ((s0 + s1) + (s2 + s3)) * 0.125f;
            am[c][e] = tanhf(sim) + adj[c * 64 + e];
        }
    }
    __syncthreads();
    if (tid < 64) {
        int c = tid;
        unsigned long long sel = 0ull;
        for (int it = 0; it < 8; it++) {
            float best = -1e38f; int bi = 0;
            for (int e = 0; e < 64; e++) {
                float v = am[c][e];
                bool ok = (((sel >> e) & 1ull) == 0ull) && (v > best);
                best = ok ? v : best;
                bi = ok ? e : bi;
            }
            sel |= (1ull << bi);
        }
        sel &= ~(1ull << c);
        for (int e = 0; e < 64; e++)
            if (am[c][e] == 0.f) sel &= ~(1ull << e);
        masks[b * 64 + c] = sel;
    }
}

// ---------------------------------------------------------------------------
// GAT + final LN, MFMA version (unchanged from R3 — passes).
__global__ __launch_bounds__(256, 1)
void gat_kernel(float* __restrict__ Htemp,
                const unsigned short* __restrict__ gwb,
                const float* __restrict__ waS, const float* __restrict__ waD,
                const float* __restrict__ gbias,
                const unsigned long long* __restrict__ masks,
                const float* __restrict__ sg, const float* __restrict__ sb) {
    __shared__ unsigned short Htb[64][132];
    __shared__ double ovl_d[3264];
    __shared__ float asrcF[4][64], adstF[4][64];
    __shared__ float pmax[4][64], psum[4][64];
    __shared__ unsigned long long mk[64];

    unsigned short (*xhT)[68]  = (unsigned short(*)[68])ovl_d;
    unsigned short (*attT)[68] = (unsigned short(*)[68])((char*)ovl_d + 17408);
    float (*part)[8][64]       = (float(*)[8][64])ovl_d;

    const int bp = blockIdx.x;
    const int b = bp >> 7, p = bp & 127;
    const int tid = threadIdx.x;
    const int lane = tid & 63, wv = tid >> 6;
    const int hl = lane >> 5, l31 = lane & 31;
    const int rs = (wv & 1) * 32;
    const int cs = (wv >> 1) * 64;

    {
        int c = tid >> 2, qq = tid & 3;
        const float* src = Htemp + ((long)(b * 64 + c) * 128 + p) * 128 + qq * 32;
#pragma unroll
        for (int k = 0; k < 8; k++) {
            float4 t4 = *(const float4*)(src + 4 * k);
            ushort4 u; u.x = f2bf(t4.x); u.y = f2bf(t4.y); u.z = f2bf(t4.z); u.w = f2bf(t4.w);
            *(ushort4*)&Htb[c][qq * 32 + 4 * k] = u;
        }
    }
    if (tid < 64) mk[tid] = masks[b * 64 + tid];
    __syncthreads();

    {
        int s = lane, q = wv;
        float acc[8];
#pragma unroll
        for (int m = 0; m < 8; m++) acc[m] = 0.f;
        const unsigned int* hp = (const unsigned int*)&Htb[s][q * 32];
#pragma unroll
        for (int d2 = 0; d2 < 16; d2++) {
            unsigned int u = hp[d2];
            float f0 = __uint_as_float(u << 16);
            float f1 = __uint_as_float(u & 0xffff0000u);
            int d = q * 32 + 2 * d2;
#pragma unroll
            for (int h = 0; h < 4; h++) {
                acc[2*h]   += f0 * waS[h * 128 + d] + f1 * waS[h * 128 + d + 1];
                acc[2*h+1] += f0 * waD[h * 128 + d] + f1 * waD[h * 128 + d + 1];
            }
        }
#pragma unroll
        for (int m = 0; m < 8; m++) part[q][m][s] = acc[m];
    }
    __syncthreads();
    for (int o = tid; o < 512; o += 256) {
        int h = o >> 7, rem = o & 127, which = rem >> 6, s = rem & 63;
        int m = h * 2 + which;
        float v = part[0][m][s] + part[1][m][s] + part[2][m][s] + part[3][m][s];
        if (which == 0) asrcF[h][s] = v; else adstF[h][s] = v;
    }
    __syncthreads();

    f32x16 oacc0, oacc1;
#pragma unroll
    for (int r = 0; r < 16; r++) { oacc0[r] = 0.f; oacc1[r] = 0.f; }

    for (int h = 0; h < 4; h++) {
        f32x16 a0, a1;
#pragma unroll
        for (int r = 0; r < 16; r++) { a0[r] = 0.f; a1[r] = 0.f; }
        const unsigned short* gwh = gwb + h * 16384;
#pragma unroll
        for (int k0 = 0; k0 < 128; k0 += 16) {
            bf16x8 af = lds_frag(&Htb[rs + l31][k0 + hl * 8]);
            bf16x8 b0 = gfrag(gwh + (cs + l31) * 128 + k0 + hl * 8);
            bf16x8 b1 = gfrag(gwh + (cs + 32 + l31) * 128 + k0 + hl * 8);
            a0 = MFMA32(af, b0, a0);
            a1 = MFMA32(af, b1, a1);
        }
#pragma unroll
        for (int g = 0; g < 4; g++) {
            ushort4 u0, u1;
            u0.x = f2bf(a0[4*g]);   u0.y = f2bf(a0[4*g+1]);
            u0.z = f2bf(a0[4*g+2]); u0.w = f2bf(a0[4*g+3]);
            u1.x = f2bf(a1[4*g]);   u1.y = f2bf(a1[4*g+1]);
            u1.z = f2bf(a1[4*g+2]); u1.w = f2bf(a1[4*g+3]);
            int so = rs + 4 * hl + 8 * g;
            *(ushort4*)&xhT[cs + l31][so]      = u0;
            *(ushort4*)&xhT[cs + 32 + l31][so] = u1;
        }
        __syncthreads();

        {
            int t = lane;
            float adv = adstF[h][t];
            float ev[16];
            float mx = -1e30f;
#pragma unroll
            for (int i = 0; i < 16; i++) {
                int s = wv * 16 + i;
                float e = asrcF[h][s] + adv;
                e = (e > 0.f) ? e : 0.2f * e;
                ev[i] = e;
                if ((mk[s] >> t) & 1ull) mx = fmaxf(mx, e);
            }
            pmax[wv][t] = mx;
            __syncthreads();
            float M = fmaxf(fmaxf(pmax[0][t], pmax[1][t]), fmaxf(pmax[2][t], pmax[3][t]));
            float sm = 0.f;
#pragma unroll
            for (int i = 0; i < 16; i++) {
                int s = wv * 16 + i;
                float w = ((mk[s] >> t) & 1ull) ? __expf(ev[i] - M) : 0.f;
                ev[i] = w; sm += w;
            }
            psum[wv][t] = sm;
            __syncthreads();
            float S = psum[0][t] + psum[1][t] + psum[2][t] + psum[3][t];
            float rinv = (S > 0.f) ? 1.f / S : 0.f;
#pragma unroll
            for (int g = 0; g < 4; g++) {
                ushort4 u;
                u.x = f2bf(ev[4*g]   * rinv); u.y = f2bf(ev[4*g+1] * rinv);
                u.z = f2bf(ev[4*g+2] * rinv); u.w = f2bf(ev[4*g+3] * rinv);
                *(ushort4*)&attT[t][wv * 16 + 4 * g] = u;
            }
        }
        __syncthreads();

#pragma unroll
        for (int k0 = 0; k0 < 64; k0 += 16) {
            bf16x8 af = lds_frag(&attT[rs + l31][k0 + hl * 8]);
            bf16x8 b0 = lds_frag(&xhT[cs + l31][k0 + hl * 8]);
            bf16x8 b1 = lds_frag(&xhT[cs + 32 + l31][k0 + hl * 8]);
            oacc0 = MFMA32(af, b0, oacc0);
            oacc1 = MFMA32(af, b1, oacc1);
        }
        __syncthreads();
    }

    float gb0 = gbias[cs + l31], gb1 = gbias[cs + 32 + l31];
    float v0[16], v1[16];
#pragma unroll
    for (int r = 0; r < 16; r++) {
        int c = rs + rowmap(r, hl);
        v0[r] = oacc0[r] * 0.25f + gb0 + bf2f(Htb[c][cs + l31]);
        v1[r] = oacc1[r] * 0.25f + gb1 + bf2f(Htb[c][cs + 32 + l31]);
    }
#pragma unroll
    for (int r = 0; r < 16; r++) {
        float s = v0[r] + v1[r];
        float q = v0[r] * v0[r] + v1[r] * v1[r];
#pragma unroll
        for (int d = 1; d < 32; d <<= 1) { s += __shfl_xor(s, d); q += __shfl_xor(q, d); }
        if (l31 == 0) {
            int c = rs + rowmap(r, hl);
            pmax[wv >> 1][c] = s;
            psum[wv >> 1][c] = q;
        }
    }
    __syncthreads();
    float sgv0 = sg[cs + l31], sbv0 = sb[cs + l31];
    float sgv1 = sg[cs + 32 + l31], sbv1 = sb[cs + 32 + l31];
#pragma unroll
    for (int r = 0; r < 16; r++) {
        int c = rs + rowmap(r, hl);
        float sum = pmax[0][c] + pmax[1][c];
        float sq  = psum[0][c] + psum[1][c];
        float mu = sum * 0.0078125f;
        float var = sq * 0.0078125f - mu * mu;
        float rsd = rsqrtf(fmaxf(var, 0.f) + 1e-5f);
        float* orow = Htemp + ((long)(b * 64 + c) * 128 + p) * 128;
        orow[cs + l31]      = (v0[r] - mu) * rsd * sgv0 + sbv0;
        orow[cs + 32 + l31] = (v1[r] - mu) * rsd * sgv1 + sbv1;
    }
}

// ---------------------------------------------------------------------------
extern "C" void kernel_launch(void* const* d_in, const int* in_sizes, int n_in,
                              void* d_out, int out_size, void* d_ws, size_t ws_size,
                              hipStream_t stream) {
    const float* Hin        = (const float*)d_in[0];
    const float* static_adj = (const float*)d_in[1];
    const float* attn_in_w  = (const float*)d_in[2];
    const float* attn_in_b  = (const float*)d_in[3];
    const float* attn_out_w = (const float*)d_in[4];
    const float* attn_out_b = (const float*)d_in[5];
    const float* ln1_g      = (const float*)d_in[6];
    const float* ln1_b      = (const float*)d_in[7];
    const float* ln2_g      = (const float*)d_in[8];
    const float* ln2_b      = (const float*)d_in[9];
    const float* ff1_w      = (const float*)d_in[10];
    const float* ff1_b      = (const float*)d_in[11];
    const float* ff2_w      = (const float*)d_in[12];
    const float* ff2_b      = (const float*)d_in[13];
    const float* tnorm_g    = (const float*)d_in[14];
    const float* tnorm_b    = (const float*)d_in[15];
    const float* q_w        = (const float*)d_in[16];
    const float* q_b        = (const float*)d_in[17];
    const float* k_w        = (const float*)d_in[18];
    const float* k_b        = (const float*)d_in[19];
    const float* gat_w      = (const float*)d_in[20];
    const float* gat_att_src= (const float*)d_in[21];
    const float* gat_att_dst= (const float*)d_in[22];
    const float* gat_bias   = (const float*)d_in[23];
    const float* snorm_g    = (const float*)d_in[24];
    const float* snorm_b    = (const float*)d_in[25];

    float* out = (float*)d_out;   // H_temp (then overwritten by final result)
    char* ws = (char*)d_ws;
    unsigned short* wb = (unsigned short*)ws;                 // 524288 B (bf16 weights)
    const unsigned short* wqkv_b = wb;
    const unsigned short* wout_b = wb + 49152;
    const unsigned short* w1_b   = wb + 65536;
    const unsigned short* w2_b   = wb + 131072;
    const unsigned short* gw_b   = wb + 196608;
    unsigned long long* masks = (unsigned long long*)(ws + 524288);   // 8192 B
    float* Hs  = (float*)(ws + 532480);                               // 524288 B
    float* waS = (float*)(ws + 1056768);                              // 2048 B
    float* waD = (float*)(ws + 1058816);                              // 2048 B

    hipLaunchKernelGGL(wconv_kernel, dim3(1024), dim3(256), 0, stream,
                       attn_in_w, attn_out_w, ff1_w, ff2_w, gat_w, wb);
    hipLaunchKernelGGL(wa_kernel, dim3(4), dim3(256), 0, stream,
                       gat_w, gat_att_src, gat_att_dst, waS, waD);
    hipLaunchKernelGGL(temporal_kernel, dim3(1024), dim3(256), 0, stream,
                       Hin, wqkv_b, attn_in_b, wout_b, attn_out_b,
                       ln1_g, ln1_b, ln2_g, ln2_b,
                       w1_b, ff1_b, w2_b, ff2_b, tnorm_g, tnorm_b, out);
    hipLaunchKernelGGL(hs_kernel, dim3(512), dim3(256), 0, stream, out, Hs);
    hipLaunchKernelGGL(graph_kernel, dim3(16), dim3(256), 0, stream,
                       Hs, q_w, q_b, k_w, k_b, static_adj, masks);
    hipLaunchKernelGGL(gat_kernel, dim3(2048), dim3(256), 0, stream,
                       out, gw_b, waS, waD, gat_bias,
                       masks, snorm_g, snorm_b);
}